// Round 3
// baseline (4187.378 us; speedup 1.0000x reference)
//
#include <hip/hip_runtime.h>
#include <hip/hip_bf16.h>

#define NN 50000
#define EE 600000
#define AA 8
#define CC 128
#define TT 16
#define TE 4
#define LL 4
#define BB 256
#define ENC 128
#define NCLS 10

__device__ __forceinline__ float b2f(ushort u) {
    union { float f; uint32_t i; } v; v.i = ((uint32_t)u) << 16; return v.f;
}

// f32 -> bf16 round-to-nearest-even, bit-level (no __hip_bfloat16 member deps)
__device__ __forceinline__ ushort f2b(float f) {
    union { float f; uint32_t i; } v; v.f = f;
    uint32_t x = v.i;
    x += 0x7FFFu + ((x >> 16) & 1u);
    return (ushort)(x >> 16);
}

// Adaptive float load: isf=1 -> buffer is f32, isf=0 -> buffer is bf16
__device__ __forceinline__ float ldw(const void* p, long i, int isf) {
    return isf ? ((const float*)p)[i] : b2f(((const ushort*)p)[i]);
}

// ---------------- dtype sniff: decide bf16 vs f32 from W_enc bit patterns ----------------
__global__ void sniff_kernel(int* flag, const void* W_enc_raw) {
    const ushort* u = (const ushort*)W_enc_raw;
    int good = 0;
    for (int i = 0; i < 256; ++i) {
        ushort v = u[i];
        int ex = (v >> 7) & 0xFF;
        if (v == 0 || (ex >= 100 && ex <= 126)) ++good;
    }
    // bf16 normals(0.05): ~256 good. f32 misread: ~140 good.
    *flag = (good >= 230) ? 0 : 1;   // 0 = bf16, 1 = f32
}

// ---------------- embed: x[n] = [type_emb[type[n]], mean(attr_emb[attrs])] ----------------
__global__ __launch_bounds__(256) void embed_kernel(
    float* __restrict__ x, const int* __restrict__ x_type, const int* __restrict__ x_attrs,
    const int* __restrict__ x_mask, const void* __restrict__ type_emb,
    const void* __restrict__ attr_emb, const int* __restrict__ flag) {
    const int isf = *flag;
    int idx = blockIdx.x * 256 + threadIdx.x;
    int n = idx >> 6, c = idx & 63;
    if (n >= NN) return;
    int ty = x_type[n];
    x[n * CC + c] = ldw(type_emb, ty * 64 + c, isf);
    int cnt = x_mask[n];
    float s = 0.f;
    for (int a = 0; a < cnt; ++a) s += ldw(attr_emb, x_attrs[n * AA + a] * 64 + c, isf);
    x[n * CC + 64 + c] = s / (float)cnt;
}

// ---------------- msg GEMM: h[n][d] = sum_c x[n][c] * W[c][d]  (h stored bf16) ----------------
__global__ __launch_bounds__(256) void msg_kernel(
    ushort* __restrict__ h, const float* __restrict__ x, const void* __restrict__ Wbase,
    long Woff, const int* __restrict__ flag) {
    const int isf = *flag;
    __shared__ float x_s[32][33];
    __shared__ float w_s[32][129];
    int tid = threadIdx.x;
    int a = tid & 31, g = tid >> 5, r0 = g * 4;
    int node0 = blockIdx.x * 32;
    float acc[4][4];
#pragma unroll
    for (int i = 0; i < 4; ++i)
#pragma unroll
        for (int j = 0; j < 4; ++j) acc[i][j] = 0.f;
    for (int kc = 0; kc < 4; ++kc) {
        __syncthreads();
#pragma unroll
        for (int q = 0; q < 4; ++q) {
            int nn = g + q * 8, n = node0 + nn;
            x_s[a][nn] = (n < NN) ? x[n * CC + kc * 32 + a] : 0.f;
        }
#pragma unroll
        for (int q = 0; q < 16; ++q) {
            int d = tid & 127, kk = (tid >> 7) + q * 2;
            w_s[kk][d] = ldw(Wbase, Woff + (kc * 32 + kk) * CC + d, isf);
        }
        __syncthreads();
#pragma unroll 4
        for (int k = 0; k < 32; ++k) {
            float xv[4], wv[4];
#pragma unroll
            for (int i = 0; i < 4; ++i) xv[i] = x_s[k][r0 + i];
#pragma unroll
            for (int j = 0; j < 4; ++j) wv[j] = w_s[k][a + 32 * j];
#pragma unroll
            for (int i = 0; i < 4; ++i)
#pragma unroll
                for (int j = 0; j < 4; ++j) acc[i][j] += xv[i] * wv[j];
        }
    }
#pragma unroll
    for (int i = 0; i < 4; ++i) {
        int n = node0 + r0 + i;
        if (n < NN)
#pragma unroll
            for (int j = 0; j < 4; ++j)
                h[n * CC + a + 32 * j] = f2b(acc[i][j]);
    }
}

// ---------------- scatter: m[dst] += h[src] for edges of type t ----------------
__global__ __launch_bounds__(256) void scatter_kernel(
    float* __restrict__ m, const ushort* __restrict__ h, const int* __restrict__ edge_index,
    const int* __restrict__ edge_attr, int t) {
    int e = blockIdx.x * 2 + (threadIdx.x >> 7);
    int c = threadIdx.x & 127;
    if (edge_attr[e] != t) return;
    int s = edge_index[e];
    int d = edge_index[EE + e];
    atomicAdd(&m[d * CC + c], b2f(h[s * CC + c]));
}

// ---------------- fused GRU: x = GRU(m, x) in place ----------------
__global__ __launch_bounds__(256) void gru_kernel(
    float* __restrict__ x, const float* __restrict__ m,
    const void* __restrict__ Wih, const void* __restrict__ Whh,
    const void* __restrict__ bih, const void* __restrict__ bhh,
    const int* __restrict__ flag) {
    const int isf = *flag;
    __shared__ float m_s[32][33];
    __shared__ float x_s[32][33];
    __shared__ float wi_s[32][129];
    __shared__ float wh_s[32][129];
    int tid = threadIdx.x;
    int a = tid & 31, g = tid >> 5, r0 = g * 4;
    int node0 = blockIdx.x * 32;
    float rr[4][4], zz[4][4];
    for (int s = 0; s < 3; ++s) {
        float acc_i[4][4], acc_h[4][4];
#pragma unroll
        for (int i = 0; i < 4; ++i)
#pragma unroll
            for (int j = 0; j < 4; ++j) {
                int col = a + 32 * j;
                acc_i[i][j] = ldw(bih, s * CC + col, isf);
                acc_h[i][j] = ldw(bhh, s * CC + col, isf);
            }
        for (int kc = 0; kc < 4; ++kc) {
            __syncthreads();
#pragma unroll
            for (int q = 0; q < 4; ++q) {
                int nn = g + q * 8, n = node0 + nn;
                float mv = 0.f, xv = 0.f;
                if (n < NN) { mv = m[n * CC + kc * 32 + a]; xv = x[n * CC + kc * 32 + a]; }
                m_s[a][nn] = mv; x_s[a][nn] = xv;
            }
#pragma unroll
            for (int q = 0; q < 16; ++q) {
                int j = g + q * 8;
                wi_s[a][j] = ldw(Wih, (s * CC + j) * CC + kc * 32 + a, isf);
                wh_s[a][j] = ldw(Whh, (s * CC + j) * CC + kc * 32 + a, isf);
            }
            __syncthreads();
#pragma unroll 4
            for (int k = 0; k < 32; ++k) {
                float mv[4], xv[4], wiv[4], whv[4];
#pragma unroll
                for (int i = 0; i < 4; ++i) { mv[i] = m_s[k][r0 + i]; xv[i] = x_s[k][r0 + i]; }
#pragma unroll
                for (int j = 0; j < 4; ++j) { wiv[j] = wi_s[k][a + 32 * j]; whv[j] = wh_s[k][a + 32 * j]; }
#pragma unroll
                for (int i = 0; i < 4; ++i)
#pragma unroll
                    for (int j = 0; j < 4; ++j) {
                        acc_i[i][j] += mv[i] * wiv[j];
                        acc_h[i][j] += xv[i] * whv[j];
                    }
            }
        }
        if (s == 0) {
#pragma unroll
            for (int i = 0; i < 4; ++i)
#pragma unroll
                for (int j = 0; j < 4; ++j) rr[i][j] = 1.f / (1.f + expf(-(acc_i[i][j] + acc_h[i][j])));
        } else if (s == 1) {
#pragma unroll
            for (int i = 0; i < 4; ++i)
#pragma unroll
                for (int j = 0; j < 4; ++j) zz[i][j] = 1.f / (1.f + expf(-(acc_i[i][j] + acc_h[i][j])));
        } else {
#pragma unroll
            for (int i = 0; i < 4; ++i) {
                int n = node0 + r0 + i;
                if (n < NN) {
#pragma unroll
                    for (int j = 0; j < 4; ++j) {
                        int col = a + 32 * j;
                        float xo = x[n * CC + col];
                        float nn_ = tanhf(acc_i[i][j] + rr[i][j] * acc_h[i][j]);
                        x[n * CC + col] = (1.f - zz[i][j]) * nn_ + zz[i][j] * xo;
                    }
                }
            }
        }
    }
}

// ---------------- aggregation: per-(graph,type) sums + counts ----------------
__global__ __launch_bounds__(256) void agg_kernel(
    float* __restrict__ sums, float* __restrict__ cnt, const float* __restrict__ x,
    const int* __restrict__ batch, const int* __restrict__ x_type) {
    int idx = blockIdx.x * 256 + threadIdx.x;
    int n = idx >> 7, c = idx & 127;
    int seg = batch[n] * TT + x_type[n];
    atomicAdd(&sums[seg * CC + c], x[idx]);
    if (c == 0) atomicAdd(&cnt[seg], 1.0f);
}

// ---------------- final: mean, attention-softmax, flatten, enc, dec ----------------
__global__ __launch_bounds__(256) void final_kernel(
    void* __restrict__ out, const float* __restrict__ sums, const float* __restrict__ cnt,
    const void* __restrict__ w_attn, const void* __restrict__ b_attn,
    const void* __restrict__ W_enc, const void* __restrict__ b_enc,
    const void* __restrict__ W_dec, const void* __restrict__ b_dec,
    const int* __restrict__ flag) {
    const int isf = *flag;
    __shared__ float agg_s[TT][CC];
    __shared__ float wpart[TT][8];
    __shared__ float attn_s[TT];
    __shared__ float enc_s[2][ENC];
    int b = blockIdx.x, tid = threadIdx.x;
#pragma unroll
    for (int q = 0; q < 8; ++q) {
        int idx = tid + q * 256;
        int t = idx >> 7, c = idx & 127;
        float cv = cnt[b * TT + t];
        agg_s[t][c] = cv > 0.f ? sums[(b * TT + t) * CC + c] / cv : 0.f;
    }
    __syncthreads();
    if (tid < 128) {
        int t = tid >> 3, p = tid & 7;
        float acc = 0.f;
        for (int i = 0; i < 16; ++i) acc += agg_s[t][p * 16 + i] * ldw(w_attn, p * 16 + i, isf);
        wpart[t][p] = acc;
    }
    __syncthreads();
    if (tid < 16) {
        float acc = ldw(b_attn, 0, isf);
        for (int p = 0; p < 8; ++p) acc += wpart[tid][p];
        attn_s[tid] = acc;
    }
    __syncthreads();
    if (tid == 0) {
        float mx = attn_s[0];
        for (int t = 1; t < TT; ++t) mx = fmaxf(mx, attn_s[t]);
        float ssum = 0.f, ex[TT];
        for (int t = 0; t < TT; ++t) { ex[t] = expf(attn_s[t] - mx); ssum += ex[t]; }
        for (int t = 0; t < TT; ++t) attn_s[t] = ex[t] / ssum;
    }
    __syncthreads();
#pragma unroll
    for (int q = 0; q < 8; ++q) {
        int idx = tid + q * 256;
        int t = idx >> 7, c = idx & 127;
        agg_s[t][c] *= attn_s[t];
    }
    __syncthreads();
    {
        int half = tid >> 7, j = tid & 127;
        const float* flat = &agg_s[0][0];
        float acc = 0.f;
        for (int i = half * 1024; i < half * 1024 + 1024; ++i)
            acc += flat[i] * ldw(W_enc, i * ENC + j, isf);
        enc_s[half][j] = acc;
    }
    __syncthreads();
    if (tid < 128) enc_s[0][tid] = enc_s[0][tid] + enc_s[1][tid] + ldw(b_enc, tid, isf);
    __syncthreads();
    if (tid < NCLS) {
        float acc = ldw(b_dec, tid, isf);
        for (int j = 0; j < ENC; ++j) acc += enc_s[0][j] * ldw(W_dec, j * NCLS + tid, isf);
        int oi = b * NCLS + tid;
        if (isf) ((float*)out)[oi] = acc;
        else ((ushort*)out)[oi] = f2b(acc);
    }
}

extern "C" void kernel_launch(void* const* d_in, const int* in_sizes, int n_in,
                              void* d_out, int out_size, void* d_ws, size_t ws_size,
                              hipStream_t stream) {
    const int* x_type      = (const int*)d_in[0];
    const int* x_attrs     = (const int*)d_in[1];
    const int* x_mask      = (const int*)d_in[2];
    const int* edge_index  = (const int*)d_in[3];
    const int* edge_attr   = (const int*)d_in[4];
    // d_in[5] = num_graphs (constant 256)
    const int* batch       = (const int*)d_in[6];
    const void* type_emb   = d_in[7];
    const void* attr_emb   = d_in[8];
    const void* W_msg      = d_in[9];
    const void* W_ih       = d_in[10];
    const void* W_hh       = d_in[11];
    const void* b_ih       = d_in[12];
    const void* b_hh       = d_in[13];
    const void* w_attn     = d_in[14];
    const void* b_attn     = d_in[15];
    const void* W_enc      = d_in[16];
    const void* b_enc      = d_in[17];
    const void* W_dec      = d_in[18];
    const void* b_dec      = d_in[19];

    float*  x    = (float*)d_ws;                       // N*C f32
    float*  m    = x + (size_t)NN * CC;                // N*C f32
    ushort* h    = (ushort*)(m + (size_t)NN * CC);     // N*C bf16
    float*  sums = (float*)(h + (size_t)NN * CC);      // B*T*C f32
    float*  cnt  = sums + (size_t)BB * TT * CC;        // B*T f32
    int*    flag = (int*)(cnt + (size_t)BB * TT);      // 1 int

    sniff_kernel<<<1, 1, 0, stream>>>(flag, W_enc);

    embed_kernel<<<(NN * 64 + 255) / 256, 256, 0, stream>>>(x, x_type, x_attrs, x_mask,
                                                            type_emb, attr_emb, flag);

    const int gemm_grid = (NN + 31) / 32;
    for (int l = 0; l < LL; ++l) {
        hipMemsetAsync(m, 0, (size_t)NN * CC * sizeof(float), stream);
        for (int t = 0; t < TE; ++t) {
            msg_kernel<<<gemm_grid, 256, 0, stream>>>(h, x, W_msg,
                                                      (long)(l * TE + t) * CC * CC, flag);
            scatter_kernel<<<EE / 2, 256, 0, stream>>>(m, h, edge_index, edge_attr, t);
        }
        gru_kernel<<<gemm_grid, 256, 0, stream>>>(x, m, W_ih, W_hh, b_ih, b_hh, flag);
    }

    hipMemsetAsync(sums, 0, (size_t)(BB * TT * CC + BB * TT) * sizeof(float), stream);
    agg_kernel<<<(NN * CC) / 256, 256, 0, stream>>>(sums, cnt, x, batch, x_type);
    final_kernel<<<BB, 256, 0, stream>>>(d_out, sums, cnt, w_attn, b_attn,
                                         W_enc, b_enc, W_dec, b_dec, flag);
}

// Round 4
// 3252.727 us; speedup vs baseline: 1.2873x; 1.2873x over previous
//
#include <hip/hip_runtime.h>
#include <hip/hip_bf16.h>

#define NN 50000
#define EE 600000
#define AA 8
#define CC 128
#define TT 16
#define TE 4
#define LL 4
#define BB 256
#define ENC 128
#define NCLS 10

typedef __attribute__((ext_vector_type(8))) short bf16x8;
typedef __attribute__((ext_vector_type(4))) float fx4;

__device__ __forceinline__ float b2f(ushort u) {
    union { float f; uint32_t i; } v; v.i = ((uint32_t)u) << 16; return v.f;
}
__device__ __forceinline__ ushort f2b(float f) {
    union { float f; uint32_t i; } v; v.f = f;
    uint32_t x = v.i;
    x += 0x7FFFu + ((x >> 16) & 1u);
    return (ushort)(x >> 16);
}
__device__ __forceinline__ float ldw(const void* p, long i, int isf) {
    return isf ? ((const float*)p)[i] : b2f(((const ushort*)p)[i]);
}
// pack 8 contiguous f32 -> bf16x8 fragment (16B-aligned source)
__device__ __forceinline__ bf16x8 packfrag(const float* p) {
    float4 a = *(const float4*)p;
    float4 b = *(const float4*)(p + 4);
    bf16x8 r;
    r[0] = (short)f2b(a.x); r[1] = (short)f2b(a.y); r[2] = (short)f2b(a.z); r[3] = (short)f2b(a.w);
    r[4] = (short)f2b(b.x); r[5] = (short)f2b(b.y); r[6] = (short)f2b(b.z); r[7] = (short)f2b(b.w);
    return r;
}
// load 8-element bf16 fragment from a weight buffer that may be f32 or bf16
__device__ __forceinline__ bf16x8 wfrag(const void* W, long off, int isf) {
    if (isf) return packfrag((const float*)W + off);
    return *(const bf16x8*)((const ushort*)W + off);
}

// ---------------- dtype sniff ----------------
__global__ void sniff_kernel(int* flag, const void* W_enc_raw) {
    const ushort* u = (const ushort*)W_enc_raw;
    int good = 0;
    for (int i = 0; i < 256; ++i) {
        ushort v = u[i];
        int ex = (v >> 7) & 0xFF;
        if (v == 0 || (ex >= 100 && ex <= 126)) ++good;
    }
    *flag = (good >= 230) ? 0 : 1;   // 0 = bf16, 1 = f32
}

// ---------------- transpose all W_msg into wT[l*4+t][d][c] (bf16) ----------------
__global__ __launch_bounds__(256) void wmsgT_kernel(ushort* __restrict__ wT,
                                                    const void* __restrict__ W,
                                                    const int* __restrict__ flag) {
    const int isf = *flag;
    int idx = blockIdx.x * 256 + threadIdx.x;      // 0 .. 16*128*128-1
    int lt = idx >> 14, rem = idx & 16383, d = rem >> 7, c = rem & 127;
    long src = ((long)lt << 14) + c * 128 + d;     // W[lt][c][d]
    wT[idx] = isf ? f2b(((const float*)W)[src]) : ((const ushort*)W)[src];
}

// ---------------- embed ----------------
__global__ __launch_bounds__(256) void embed_kernel(
    float* __restrict__ x, const int* __restrict__ x_type, const int* __restrict__ x_attrs,
    const int* __restrict__ x_mask, const void* __restrict__ type_emb,
    const void* __restrict__ attr_emb, const int* __restrict__ flag) {
    const int isf = *flag;
    int idx = blockIdx.x * 256 + threadIdx.x;
    int n = idx >> 6, c = idx & 63;
    if (n >= NN) return;
    int ty = x_type[n];
    x[n * CC + c] = ldw(type_emb, ty * 64 + c, isf);
    int cnt = x_mask[n];
    float s = 0.f;
    for (int a = 0; a < cnt; ++a) s += ldw(attr_emb, x_attrs[n * AA + a] * 64 + c, isf);
    x[n * CC + 64 + c] = s / (float)cnt;
}

// ---------------- msg MFMA: h2[t][n][d] = x[n][:] @ W_t for 2 types ----------------
// wT points at [2][128][128] bf16, layout [t][d][c]
__global__ __launch_bounds__(256) void msg_mfma(
    ushort* __restrict__ h2, const float* __restrict__ x, const ushort* __restrict__ wT) {
    int tid = threadIdx.x;
    int w = tid >> 6, l = tid & 63;
    int node0 = blockIdx.x * 64 + w * 16;
    int lr = l & 15, lk = (l >> 4) * 8;
    bf16x8 af[4];
#pragma unroll
    for (int ks = 0; ks < 4; ++ks)
        af[ks] = packfrag(&x[(size_t)(node0 + lr) * CC + ks * 32 + lk]);
#pragma unroll
    for (int t = 0; t < 2; ++t) {
#pragma unroll
        for (int ct = 0; ct < 8; ++ct) {
            fx4 acc = {0.f, 0.f, 0.f, 0.f};
#pragma unroll
            for (int ks = 0; ks < 4; ++ks) {
                bf16x8 bf = *(const bf16x8*)&wT[(size_t)(t * 128 + ct * 16 + lr) * 128 + ks * 32 + lk];
                acc = __builtin_amdgcn_mfma_f32_16x16x32_bf16(af[ks], bf, acc, 0, 0, 0);
            }
#pragma unroll
            for (int r = 0; r < 4; ++r) {
                int node = node0 + (l >> 4) * 4 + r;
                if (node < NN)
                    h2[((size_t)t * NN + node) * CC + ct * 16 + lr] = f2b(acc[r]);
            }
        }
    }
}

// ---------------- scatter: m[dst] += h2[t][src] for edges with type in {tbase, tbase+1} ----------------
__global__ __launch_bounds__(256) void scatter_pair(
    float* __restrict__ m, const ushort* __restrict__ h2, const int* __restrict__ ei,
    const int* __restrict__ ea, int tbase) {
    int e = blockIdx.x * 4 + (threadIdx.x >> 6);
    int cp = (threadIdx.x & 63) * 2;
    unsigned t = (unsigned)(ea[e] - tbase);
    if (t > 1u) return;
    int s = ei[e], d = ei[EE + e];
    uint hv = *(const uint*)&h2[((size_t)t * NN + s) * CC + cp];
    atomicAdd(&m[(size_t)d * CC + cp],     b2f((ushort)(hv & 0xFFFFu)));
    atomicAdd(&m[(size_t)d * CC + cp + 1], b2f((ushort)(hv >> 16)));
}

// ---------------- GRU MFMA: x = GRU(m, x) in place ----------------
__global__ __launch_bounds__(256) void gru_mfma(
    float* __restrict__ x, const float* __restrict__ m,
    const void* __restrict__ Wih, const void* __restrict__ Whh,
    const void* __restrict__ bih, const void* __restrict__ bhh,
    const int* __restrict__ flag) {
    const int isf = *flag;
    int tid = threadIdx.x;
    int w = tid >> 6, l = tid & 63;
    int node0 = blockIdx.x * 64 + w * 16;
    int lr = l & 15, lk = (l >> 4) * 8;
    bf16x8 mf[4], xf[4];
#pragma unroll
    for (int ks = 0; ks < 4; ++ks) {
        mf[ks] = packfrag(&m[(size_t)(node0 + lr) * CC + ks * 32 + lk]);
        xf[ks] = packfrag(&x[(size_t)(node0 + lr) * CC + ks * 32 + lk]);
    }
#pragma unroll
    for (int ct = 0; ct < 8; ++ct) {
        fx4 ai[3], ah[3];
#pragma unroll
        for (int s = 0; s < 3; ++s) { ai[s] = (fx4){0.f,0.f,0.f,0.f}; ah[s] = (fx4){0.f,0.f,0.f,0.f}; }
#pragma unroll
        for (int s = 0; s < 3; ++s) {
            long ob = (long)(s * 128 + ct * 16 + lr) * 128 + lk;
#pragma unroll
            for (int ks = 0; ks < 4; ++ks)
                ai[s] = __builtin_amdgcn_mfma_f32_16x16x32_bf16(mf[ks], wfrag(Wih, ob + ks * 32, isf), ai[s], 0, 0, 0);
#pragma unroll
            for (int ks = 0; ks < 4; ++ks)
                ah[s] = __builtin_amdgcn_mfma_f32_16x16x32_bf16(xf[ks], wfrag(Whh, ob + ks * 32, isf), ah[s], 0, 0, 0);
        }
        int o0 = ct * 16 + lr;
        float bi0 = ldw(bih, o0, isf),       bh0 = ldw(bhh, o0, isf);
        float bi1 = ldw(bih, 128 + o0, isf), bh1 = ldw(bhh, 128 + o0, isf);
        float bi2 = ldw(bih, 256 + o0, isf), bh2 = ldw(bhh, 256 + o0, isf);
#pragma unroll
        for (int r = 0; r < 4; ++r) {
            int node = node0 + (l >> 4) * 4 + r;
            if (node >= NN) continue;
            float ir_ = ai[0][r] + bi0, iz_ = ai[1][r] + bi1, in_ = ai[2][r] + bi2;
            float hr_ = ah[0][r] + bh0, hz_ = ah[1][r] + bh1, hn_ = ah[2][r] + bh2;
            float rg = 1.f / (1.f + expf(-(ir_ + hr_)));
            float zg = 1.f / (1.f + expf(-(iz_ + hz_)));
            float ng = tanhf(in_ + rg * hn_);
            size_t xi = (size_t)node * CC + o0;
            float xo = x[xi];
            x[xi] = (1.f - zg) * ng + zg * xo;
        }
    }
}

// ---------------- aggregation ----------------
__global__ __launch_bounds__(256) void agg_kernel(
    float* __restrict__ sums, float* __restrict__ cnt, const float* __restrict__ x,
    const int* __restrict__ batch, const int* __restrict__ x_type) {
    int idx = blockIdx.x * 256 + threadIdx.x;
    int n = idx >> 7, c = idx & 127;
    int seg = batch[n] * TT + x_type[n];
    atomicAdd(&sums[seg * CC + c], x[idx]);
    if (c == 0) atomicAdd(&cnt[seg], 1.0f);
}

// ---------------- final ----------------
__global__ __launch_bounds__(256) void final_kernel(
    void* __restrict__ out, const float* __restrict__ sums, const float* __restrict__ cnt,
    const void* __restrict__ w_attn, const void* __restrict__ b_attn,
    const void* __restrict__ W_enc, const void* __restrict__ b_enc,
    const void* __restrict__ W_dec, const void* __restrict__ b_dec,
    const int* __restrict__ flag) {
    const int isf = *flag;
    __shared__ float agg_s[TT][CC];
    __shared__ float wpart[TT][8];
    __shared__ float attn_s[TT];
    __shared__ float enc_s[2][ENC];
    int b = blockIdx.x, tid = threadIdx.x;
#pragma unroll
    for (int q = 0; q < 8; ++q) {
        int idx = tid + q * 256;
        int t = idx >> 7, c = idx & 127;
        float cv = cnt[b * TT + t];
        agg_s[t][c] = cv > 0.f ? sums[(b * TT + t) * CC + c] / cv : 0.f;
    }
    __syncthreads();
    if (tid < 128) {
        int t = tid >> 3, p = tid & 7;
        float acc = 0.f;
        for (int i = 0; i < 16; ++i) acc += agg_s[t][p * 16 + i] * ldw(w_attn, p * 16 + i, isf);
        wpart[t][p] = acc;
    }
    __syncthreads();
    if (tid < 16) {
        float acc = ldw(b_attn, 0, isf);
        for (int p = 0; p < 8; ++p) acc += wpart[tid][p];
        attn_s[tid] = acc;
    }
    __syncthreads();
    if (tid == 0) {
        float mx = attn_s[0];
        for (int t = 1; t < TT; ++t) mx = fmaxf(mx, attn_s[t]);
        float ssum = 0.f, ex[TT];
        for (int t = 0; t < TT; ++t) { ex[t] = expf(attn_s[t] - mx); ssum += ex[t]; }
        for (int t = 0; t < TT; ++t) attn_s[t] = ex[t] / ssum;
    }
    __syncthreads();
#pragma unroll
    for (int q = 0; q < 8; ++q) {
        int idx = tid + q * 256;
        int t = idx >> 7, c = idx & 127;
        agg_s[t][c] *= attn_s[t];
    }
    __syncthreads();
    {
        int half = tid >> 7, j = tid & 127;
        const float* flat = &agg_s[0][0];
        float acc = 0.f;
        for (int i = half * 1024; i < half * 1024 + 1024; ++i)
            acc += flat[i] * ldw(W_enc, i * ENC + j, isf);
        enc_s[half][j] = acc;
    }
    __syncthreads();
    if (tid < 128) enc_s[0][tid] = enc_s[0][tid] + enc_s[1][tid] + ldw(b_enc, tid, isf);
    __syncthreads();
    if (tid < NCLS) {
        float acc = ldw(b_dec, tid, isf);
        for (int j = 0; j < ENC; ++j) acc += enc_s[0][j] * ldw(W_dec, j * NCLS + tid, isf);
        int oi = b * NCLS + tid;
        if (isf) ((float*)out)[oi] = acc;
        else ((ushort*)out)[oi] = f2b(acc);
    }
}

extern "C" void kernel_launch(void* const* d_in, const int* in_sizes, int n_in,
                              void* d_out, int out_size, void* d_ws, size_t ws_size,
                              hipStream_t stream) {
    const int* x_type      = (const int*)d_in[0];
    const int* x_attrs     = (const int*)d_in[1];
    const int* x_mask      = (const int*)d_in[2];
    const int* edge_index  = (const int*)d_in[3];
    const int* edge_attr   = (const int*)d_in[4];
    const int* batch       = (const int*)d_in[6];
    const void* type_emb   = d_in[7];
    const void* attr_emb   = d_in[8];
    const void* W_msg      = d_in[9];
    const void* W_ih       = d_in[10];
    const void* W_hh       = d_in[11];
    const void* b_ih       = d_in[12];
    const void* b_hh       = d_in[13];
    const void* w_attn     = d_in[14];
    const void* b_attn     = d_in[15];
    const void* W_enc      = d_in[16];
    const void* b_enc      = d_in[17];
    const void* W_dec      = d_in[18];
    const void* b_dec      = d_in[19];

    float*  x    = (float*)d_ws;                          // N*C f32
    float*  m    = x + (size_t)NN * CC;                   // N*C f32
    ushort* h2   = (ushort*)(m + (size_t)NN * CC);        // 2*N*C bf16
    ushort* wT   = h2 + (size_t)2 * NN * CC;              // 16*128*128 bf16
    float*  sums = (float*)(wT + 16 * 128 * 128);         // B*T*C f32
    float*  cnt  = sums + (size_t)BB * TT * CC;           // B*T
    int*    flag = (int*)(cnt + (size_t)BB * TT);

    sniff_kernel<<<1, 1, 0, stream>>>(flag, W_enc);
    wmsgT_kernel<<<1024, 256, 0, stream>>>(wT, W_msg, flag);
    embed_kernel<<<(NN * 64) / 256, 256, 0, stream>>>(x, x_type, x_attrs, x_mask,
                                                      type_emb, attr_emb, flag);

    const int mfma_grid = (NN + 63) / 64;   // 782
    for (int l = 0; l < LL; ++l) {
        hipMemsetAsync(m, 0, (size_t)NN * CC * sizeof(float), stream);
        for (int p = 0; p < 2; ++p) {
            msg_mfma<<<mfma_grid, 256, 0, stream>>>(h2, x, wT + (size_t)(l * 4 + p * 2) * 128 * 128);
            scatter_pair<<<EE / 4, 256, 0, stream>>>(m, h2, edge_index, edge_attr, p * 2);
        }
        gru_mfma<<<mfma_grid, 256, 0, stream>>>(x, m, W_ih, W_hh, b_ih, b_hh, flag);
    }

    hipMemsetAsync(sums, 0, (size_t)(BB * TT * CC + BB * TT) * sizeof(float), stream);
    agg_kernel<<<(NN * CC) / 256, 256, 0, stream>>>(sums, cnt, x, batch, x_type);
    final_kernel<<<BB, 256, 0, stream>>>(d_out, sums, cnt, w_attn, b_attn,
                                         W_enc, b_enc, W_dec, b_dec, flag);
}

// Round 5
// 1504.867 us; speedup vs baseline: 2.7826x; 2.1615x over previous
//
#include <hip/hip_runtime.h>
#include <hip/hip_bf16.h>

#define NN 50000
#define EE 600000
#define AA 8
#define CC 128
#define TT 16
#define TE 4
#define LL 4
#define BB 256
#define ENC 128
#define NCLS 10

typedef __attribute__((ext_vector_type(8))) short bf16x8;
typedef __attribute__((ext_vector_type(4))) float fx4;

__device__ __forceinline__ float b2f(ushort u) {
    union { float f; uint32_t i; } v; v.i = ((uint32_t)u) << 16; return v.f;
}
__device__ __forceinline__ ushort f2b(float f) {
    union { float f; uint32_t i; } v; v.f = f;
    uint32_t x = v.i;
    x += 0x7FFFu + ((x >> 16) & 1u);
    return (ushort)(x >> 16);
}
__device__ __forceinline__ float ldw(const void* p, long i, int isf) {
    return isf ? ((const float*)p)[i] : b2f(((const ushort*)p)[i]);
}
__device__ __forceinline__ bf16x8 packfrag(const float* p) {
    float4 a = *(const float4*)p;
    float4 b = *(const float4*)(p + 4);
    bf16x8 r;
    r[0] = (short)f2b(a.x); r[1] = (short)f2b(a.y); r[2] = (short)f2b(a.z); r[3] = (short)f2b(a.w);
    r[4] = (short)f2b(b.x); r[5] = (short)f2b(b.y); r[6] = (short)f2b(b.z); r[7] = (short)f2b(b.w);
    return r;
}
__device__ __forceinline__ bf16x8 wfrag(const void* W, long off, int isf) {
    if (isf) return packfrag((const float*)W + off);
    return *(const bf16x8*)((const ushort*)W + off);
}

// ---------------- dtype sniff ----------------
__global__ void sniff_kernel(int* flag, const void* W_enc_raw) {
    const ushort* u = (const ushort*)W_enc_raw;
    int good = 0;
    for (int i = 0; i < 256; ++i) {
        ushort v = u[i];
        int ex = (v >> 7) & 0xFF;
        if (v == 0 || (ex >= 100 && ex <= 126)) ++good;
    }
    *flag = (good >= 230) ? 0 : 1;   // 0 = bf16, 1 = f32
}

// ---------------- transpose all W_msg into wT[l*4+t][d][c] (bf16) ----------------
__global__ __launch_bounds__(256) void wmsgT_kernel(ushort* __restrict__ wT,
                                                    const void* __restrict__ W,
                                                    const int* __restrict__ flag) {
    const int isf = *flag;
    int idx = blockIdx.x * 256 + threadIdx.x;
    int lt = idx >> 14, rem = idx & 16383, d = rem >> 7, c = rem & 127;
    long src = ((long)lt << 14) + c * 128 + d;
    wT[idx] = isf ? f2b(((const float*)W)[src]) : ((const ushort*)W)[src];
}

// ---------------- embed ----------------
__global__ __launch_bounds__(256) void embed_kernel(
    float* __restrict__ x, const int* __restrict__ x_type, const int* __restrict__ x_attrs,
    const int* __restrict__ x_mask, const void* __restrict__ type_emb,
    const void* __restrict__ attr_emb, const int* __restrict__ flag) {
    const int isf = *flag;
    int idx = blockIdx.x * 256 + threadIdx.x;
    int n = idx >> 6, c = idx & 63;
    if (n >= NN) return;
    int ty = x_type[n];
    x[n * CC + c] = ldw(type_emb, ty * 64 + c, isf);
    int cnt = x_mask[n];
    float s = 0.f;
    for (int a = 0; a < cnt; ++a) s += ldw(attr_emb, x_attrs[n * AA + a] * 64 + c, isf);
    x[n * CC + 64 + c] = s / (float)cnt;
}

// ---------------- CSR build ----------------
__global__ __launch_bounds__(256) void deg_kernel(int* __restrict__ cnt, const int* __restrict__ ei) {
    int e = blockIdx.x * 256 + threadIdx.x;
    if (e < EE) atomicAdd(&cnt[ei[EE + e]], 1);
}

__global__ __launch_bounds__(256) void scan1_kernel(int* __restrict__ cnt, int* __restrict__ btot) {
    __shared__ int s[256];
    int tid = threadIdx.x, i = blockIdx.x * 256 + tid;
    int v = (i < NN) ? cnt[i] : 0;
    s[tid] = v; __syncthreads();
    for (int off = 1; off < 256; off <<= 1) {
        int t = (tid >= off) ? s[tid - off] : 0; __syncthreads();
        s[tid] += t; __syncthreads();
    }
    if (i < NN) cnt[i] = s[tid] - v;            // exclusive within block
    if (tid == 255) btot[blockIdx.x] = s[255];
}

__global__ __launch_bounds__(256) void scan2_kernel(int* __restrict__ btot, int nb) {
    __shared__ int s[256];
    int tid = threadIdx.x;
    int v = (tid < nb) ? btot[tid] : 0;
    s[tid] = v; __syncthreads();
    for (int off = 1; off < 256; off <<= 1) {
        int t = (tid >= off) ? s[tid - off] : 0; __syncthreads();
        s[tid] += t; __syncthreads();
    }
    if (tid < nb) btot[tid] = s[tid] - v;       // exclusive block offsets
}

__global__ __launch_bounds__(256) void scan3_kernel(int* __restrict__ cnt, const int* __restrict__ btot) {
    int i = blockIdx.x * 256 + threadIdx.x;
    if (i < NN) cnt[i] += btot[blockIdx.x];
}

// fill: cnt holds exclusive starts; after fill cnt[d] == end_d
__global__ __launch_bounds__(256) void fill_kernel(uint* __restrict__ csr, int* __restrict__ cnt,
                                                   const int* __restrict__ ei, const int* __restrict__ ea) {
    int e = blockIdx.x * 256 + threadIdx.x;
    if (e >= EE) return;
    int d = ei[EE + e];
    int pos = atomicAdd(&cnt[d], 1);
    csr[pos] = (uint)ei[e] | ((uint)ea[e] << 16);
}

// ---------------- msg MFMA: h4[t][n][d] for all 4 types ----------------
__global__ __launch_bounds__(256) void msg_mfma4(
    ushort* __restrict__ h4, const float* __restrict__ x, const ushort* __restrict__ wT) {
    int tid = threadIdx.x;
    int w = tid >> 6, l = tid & 63;
    int node0 = blockIdx.x * 64 + w * 16;
    int lr = l & 15, lk = (l >> 4) * 8;
    bf16x8 af[4];
#pragma unroll
    for (int ks = 0; ks < 4; ++ks)
        af[ks] = packfrag(&x[(size_t)(node0 + lr) * CC + ks * 32 + lk]);
#pragma unroll
    for (int t = 0; t < 4; ++t) {
#pragma unroll
        for (int ct = 0; ct < 8; ++ct) {
            fx4 acc = {0.f, 0.f, 0.f, 0.f};
#pragma unroll
            for (int ks = 0; ks < 4; ++ks) {
                bf16x8 bf = *(const bf16x8*)&wT[(size_t)(t * 128 + ct * 16 + lr) * 128 + ks * 32 + lk];
                acc = __builtin_amdgcn_mfma_f32_16x16x32_bf16(af[ks], bf, acc, 0, 0, 0);
            }
#pragma unroll
            for (int r = 0; r < 4; ++r) {
                int node = node0 + (l >> 4) * 4 + r;
                if (node < NN)
                    h4[((size_t)t * NN + node) * CC + ct * 16 + lr] = f2b(acc[r]);
            }
        }
    }
}

// ---------------- gather: m[d] = sum_{e: dst=d} h4[type_e][src_e]  (wave per node) ----------------
__global__ __launch_bounds__(256) void gather_kernel(
    ushort* __restrict__ mbf, const ushort* __restrict__ h4,
    const uint* __restrict__ csr, const int* __restrict__ endp) {
    int w = threadIdx.x >> 6, l = threadIdx.x & 63;
    int node = blockIdx.x * 4 + w;
    int start = (node == 0) ? 0 : endp[node - 1];
    int end = endp[node];
    int c0 = l * 2;
    float s0 = 0.f, s1 = 0.f;
    for (int i = start; i < end; ++i) {
        uint pk = csr[i];
        uint src = pk & 0xFFFFu, t = pk >> 16;
        uint hv = *(const uint*)&h4[(((size_t)t * NN + src) << 7) + c0];
        s0 += b2f((ushort)(hv & 0xFFFFu));
        s1 += b2f((ushort)(hv >> 16));
    }
    *(uint*)&mbf[((size_t)node << 7) + c0] = (uint)f2b(s0) | ((uint)f2b(s1) << 16);
}

// ---------------- GRU MFMA: x = GRU(m, x) in place (m already bf16) ----------------
__global__ __launch_bounds__(256) void gru_mfma(
    float* __restrict__ x, const ushort* __restrict__ mbf,
    const void* __restrict__ Wih, const void* __restrict__ Whh,
    const void* __restrict__ bih, const void* __restrict__ bhh,
    const int* __restrict__ flag) {
    const int isf = *flag;
    int tid = threadIdx.x;
    int w = tid >> 6, l = tid & 63;
    int node0 = blockIdx.x * 64 + w * 16;
    int lr = l & 15, lk = (l >> 4) * 8;
    bf16x8 mf[4], xf[4];
#pragma unroll
    for (int ks = 0; ks < 4; ++ks) {
        mf[ks] = *(const bf16x8*)&mbf[(size_t)(node0 + lr) * CC + ks * 32 + lk];
        xf[ks] = packfrag(&x[(size_t)(node0 + lr) * CC + ks * 32 + lk]);
    }
#pragma unroll
    for (int ct = 0; ct < 8; ++ct) {
        fx4 ai[3], ah[3];
#pragma unroll
        for (int s = 0; s < 3; ++s) { ai[s] = (fx4){0.f,0.f,0.f,0.f}; ah[s] = (fx4){0.f,0.f,0.f,0.f}; }
#pragma unroll
        for (int s = 0; s < 3; ++s) {
            long ob = (long)(s * 128 + ct * 16 + lr) * 128 + lk;
#pragma unroll
            for (int ks = 0; ks < 4; ++ks)
                ai[s] = __builtin_amdgcn_mfma_f32_16x16x32_bf16(mf[ks], wfrag(Wih, ob + ks * 32, isf), ai[s], 0, 0, 0);
#pragma unroll
            for (int ks = 0; ks < 4; ++ks)
                ah[s] = __builtin_amdgcn_mfma_f32_16x16x32_bf16(xf[ks], wfrag(Whh, ob + ks * 32, isf), ah[s], 0, 0, 0);
        }
        int o0 = ct * 16 + lr;
        float bi0 = ldw(bih, o0, isf),       bh0 = ldw(bhh, o0, isf);
        float bi1 = ldw(bih, 128 + o0, isf), bh1 = ldw(bhh, 128 + o0, isf);
        float bi2 = ldw(bih, 256 + o0, isf), bh2 = ldw(bhh, 256 + o0, isf);
#pragma unroll
        for (int r = 0; r < 4; ++r) {
            int node = node0 + (l >> 4) * 4 + r;
            if (node >= NN) continue;
            float ir_ = ai[0][r] + bi0, iz_ = ai[1][r] + bi1, in_ = ai[2][r] + bi2;
            float hr_ = ah[0][r] + bh0, hz_ = ah[1][r] + bh1, hn_ = ah[2][r] + bh2;
            float rg = 1.f / (1.f + expf(-(ir_ + hr_)));
            float zg = 1.f / (1.f + expf(-(iz_ + hz_)));
            float ng = tanhf(in_ + rg * hn_);
            size_t xi = (size_t)node * CC + o0;
            float xo = x[xi];
            x[xi] = (1.f - zg) * ng + zg * xo;
        }
    }
}

// ---------------- aggregation ----------------
__global__ __launch_bounds__(256) void agg_kernel(
    float* __restrict__ sums, float* __restrict__ cnt, const float* __restrict__ x,
    const int* __restrict__ batch, const int* __restrict__ x_type) {
    int idx = blockIdx.x * 256 + threadIdx.x;
    int n = idx >> 7, c = idx & 127;
    int seg = batch[n] * TT + x_type[n];
    atomicAdd(&sums[seg * CC + c], x[idx]);
    if (c == 0) atomicAdd(&cnt[seg], 1.0f);
}

// ---------------- final ----------------
__global__ __launch_bounds__(256) void final_kernel(
    void* __restrict__ out, const float* __restrict__ sums, const float* __restrict__ cnt,
    const void* __restrict__ w_attn, const void* __restrict__ b_attn,
    const void* __restrict__ W_enc, const void* __restrict__ b_enc,
    const void* __restrict__ W_dec, const void* __restrict__ b_dec,
    const int* __restrict__ flag) {
    const int isf = *flag;
    __shared__ float agg_s[TT][CC];
    __shared__ float wpart[TT][8];
    __shared__ float attn_s[TT];
    __shared__ float enc_s[2][ENC];
    int b = blockIdx.x, tid = threadIdx.x;
#pragma unroll
    for (int q = 0; q < 8; ++q) {
        int idx = tid + q * 256;
        int t = idx >> 7, c = idx & 127;
        float cv = cnt[b * TT + t];
        agg_s[t][c] = cv > 0.f ? sums[(b * TT + t) * CC + c] / cv : 0.f;
    }
    __syncthreads();
    if (tid < 128) {
        int t = tid >> 3, p = tid & 7;
        float acc = 0.f;
        for (int i = 0; i < 16; ++i) acc += agg_s[t][p * 16 + i] * ldw(w_attn, p * 16 + i, isf);
        wpart[t][p] = acc;
    }
    __syncthreads();
    if (tid < 16) {
        float acc = ldw(b_attn, 0, isf);
        for (int p = 0; p < 8; ++p) acc += wpart[tid][p];
        attn_s[tid] = acc;
    }
    __syncthreads();
    if (tid == 0) {
        float mx = attn_s[0];
        for (int t = 1; t < TT; ++t) mx = fmaxf(mx, attn_s[t]);
        float ssum = 0.f, ex[TT];
        for (int t = 0; t < TT; ++t) { ex[t] = expf(attn_s[t] - mx); ssum += ex[t]; }
        for (int t = 0; t < TT; ++t) attn_s[t] = ex[t] / ssum;
    }
    __syncthreads();
#pragma unroll
    for (int q = 0; q < 8; ++q) {
        int idx = tid + q * 256;
        int t = idx >> 7, c = idx & 127;
        agg_s[t][c] *= attn_s[t];
    }
    __syncthreads();
    {
        int half = tid >> 7, j = tid & 127;
        const float* flat = &agg_s[0][0];
        float acc = 0.f;
        for (int i = half * 1024; i < half * 1024 + 1024; ++i)
            acc += flat[i] * ldw(W_enc, i * ENC + j, isf);
        enc_s[half][j] = acc;
    }
    __syncthreads();
    if (tid < 128) enc_s[0][tid] = enc_s[0][tid] + enc_s[1][tid] + ldw(b_enc, tid, isf);
    __syncthreads();
    if (tid < NCLS) {
        float acc = ldw(b_dec, tid, isf);
        for (int j = 0; j < ENC; ++j) acc += enc_s[0][j] * ldw(W_dec, j * NCLS + tid, isf);
        int oi = b * NCLS + tid;
        if (isf) ((float*)out)[oi] = acc;
        else ((ushort*)out)[oi] = f2b(acc);
    }
}

extern "C" void kernel_launch(void* const* d_in, const int* in_sizes, int n_in,
                              void* d_out, int out_size, void* d_ws, size_t ws_size,
                              hipStream_t stream) {
    const int* x_type      = (const int*)d_in[0];
    const int* x_attrs     = (const int*)d_in[1];
    const int* x_mask      = (const int*)d_in[2];
    const int* edge_index  = (const int*)d_in[3];
    const int* edge_attr   = (const int*)d_in[4];
    const int* batch       = (const int*)d_in[6];
    const void* type_emb   = d_in[7];
    const void* attr_emb   = d_in[8];
    const void* W_msg      = d_in[9];
    const void* W_ih       = d_in[10];
    const void* W_hh       = d_in[11];
    const void* b_ih       = d_in[12];
    const void* b_hh       = d_in[13];
    const void* w_attn     = d_in[14];
    const void* b_attn     = d_in[15];
    const void* W_enc      = d_in[16];
    const void* b_enc      = d_in[17];
    const void* W_dec      = d_in[18];
    const void* b_dec      = d_in[19];

    char* p = (char*)d_ws;
    float*  x    = (float*)p;            p += (size_t)NN * CC * 4;       // 25.6 MB
    ushort* mbf  = (ushort*)p;           p += (size_t)NN * CC * 2;       // 12.8 MB
    ushort* h4   = (ushort*)p;           p += (size_t)4 * NN * CC * 2;   // 51.2 MB
    ushort* wT   = (ushort*)p;           p += (size_t)16 * 128 * 128 * 2;
    float*  sums = (float*)p;            p += (size_t)BB * TT * CC * 4;
    float*  cnta = (float*)p;            p += (size_t)BB * TT * 4;
    uint*   csr  = (uint*)p;             p += (size_t)EE * 4;            // 2.4 MB
    int*    cptr = (int*)p;              p += (size_t)NN * 4;            // 0.2 MB
    int*    btot = (int*)p;              p += 256 * 4;
    int*    flag = (int*)p;

    sniff_kernel<<<1, 1, 0, stream>>>(flag, W_enc);
    wmsgT_kernel<<<1024, 256, 0, stream>>>(wT, W_msg, flag);
    embed_kernel<<<(NN * 64) / 256, 256, 0, stream>>>(x, x_type, x_attrs, x_mask,
                                                      type_emb, attr_emb, flag);

    // ---- CSR build (once) ----
    const int NB = (NN + 255) / 256;   // 196
    hipMemsetAsync(cptr, 0, (size_t)NN * sizeof(int), stream);
    deg_kernel<<<(EE + 255) / 256, 256, 0, stream>>>(cptr, edge_index);
    scan1_kernel<<<NB, 256, 0, stream>>>(cptr, btot);
    scan2_kernel<<<1, 256, 0, stream>>>(btot, NB);
    scan3_kernel<<<NB, 256, 0, stream>>>(cptr, btot);
    fill_kernel<<<(EE + 255) / 256, 256, 0, stream>>>(csr, cptr, edge_index, edge_attr);
    // after fill: cptr[d] == end offset of node d

    const int mfma_grid = (NN + 63) / 64;   // 782
    for (int l = 0; l < LL; ++l) {
        msg_mfma4<<<mfma_grid, 256, 0, stream>>>(h4, x, wT + (size_t)l * 4 * 128 * 128);
        gather_kernel<<<NN / 4, 256, 0, stream>>>(mbf, h4, csr, cptr);
        gru_mfma<<<mfma_grid, 256, 0, stream>>>(x, mbf, W_ih, W_hh, b_ih, b_hh, flag);
    }

    hipMemsetAsync(sums, 0, (size_t)(BB * TT * CC + BB * TT) * sizeof(float), stream);
    agg_kernel<<<(NN * CC) / 256, 256, 0, stream>>>(sums, cnta, x, batch, x_type);
    final_kernel<<<BB, 256, 0, stream>>>(d_out, sums, cnta, w_attn, b_attn,
                                         W_enc, b_enc, W_dec, b_dec, flag);
}

// Round 6
// 1369.525 us; speedup vs baseline: 3.0575x; 1.0988x over previous
//
#include <hip/hip_runtime.h>
#include <hip/hip_bf16.h>

#define NN 50000
#define EE 600000
#define AA 8
#define CC 128
#define TT 16
#define TE 4
#define LL 4
#define BB 256
#define ENC 128
#define NCLS 10

typedef __attribute__((ext_vector_type(8))) short bf16x8;
typedef __attribute__((ext_vector_type(4))) float fx4;

__device__ __forceinline__ float b2f(ushort u) {
    union { float f; uint32_t i; } v; v.i = ((uint32_t)u) << 16; return v.f;
}
__device__ __forceinline__ ushort f2b(float f) {
    union { float f; uint32_t i; } v; v.f = f;
    uint32_t x = v.i;
    x += 0x7FFFu + ((x >> 16) & 1u);
    return (ushort)(x >> 16);
}
__device__ __forceinline__ float ldw(const void* p, long i, int isf) {
    return isf ? ((const float*)p)[i] : b2f(((const ushort*)p)[i]);
}
__device__ __forceinline__ bf16x8 packfrag(const float* p) {
    float4 a = *(const float4*)p;
    float4 b = *(const float4*)(p + 4);
    bf16x8 r;
    r[0] = (short)f2b(a.x); r[1] = (short)f2b(a.y); r[2] = (short)f2b(a.z); r[3] = (short)f2b(a.w);
    r[4] = (short)f2b(b.x); r[5] = (short)f2b(b.y); r[6] = (short)f2b(b.z); r[7] = (short)f2b(b.w);
    return r;
}
__device__ __forceinline__ bf16x8 wfrag(const void* W, long off, int isf) {
    if (isf) return packfrag((const float*)W + off);
    return *(const bf16x8*)((const ushort*)W + off);
}
__device__ __forceinline__ float sigm(float t) { return 1.f / (1.f + __expf(-t)); }

// ---------------- dtype sniff ----------------
__global__ void sniff_kernel(int* flag, const void* W_enc_raw) {
    const ushort* u = (const ushort*)W_enc_raw;
    int good = 0;
    for (int i = 0; i < 256; ++i) {
        ushort v = u[i];
        int ex = (v >> 7) & 0xFF;
        if (v == 0 || (ex >= 100 && ex <= 126)) ++good;
    }
    *flag = (good >= 230) ? 0 : 1;   // 0 = bf16, 1 = f32
}

// ---------------- transpose all W_msg into wT[l*4+t][d][c] (bf16) ----------------
__global__ __launch_bounds__(256) void wmsgT_kernel(ushort* __restrict__ wT,
                                                    const void* __restrict__ W,
                                                    const int* __restrict__ flag) {
    const int isf = *flag;
    int idx = blockIdx.x * 256 + threadIdx.x;
    int lt = idx >> 14, rem = idx & 16383, d = rem >> 7, c = rem & 127;
    long src = ((long)lt << 14) + c * 128 + d;
    wT[idx] = isf ? f2b(((const float*)W)[src]) : ((const ushort*)W)[src];
}

// ---------------- embed: writes f32 x and bf16 mirror xbf ----------------
__global__ __launch_bounds__(256) void embed_kernel(
    float* __restrict__ x, ushort* __restrict__ xbf,
    const int* __restrict__ x_type, const int* __restrict__ x_attrs,
    const int* __restrict__ x_mask, const void* __restrict__ type_emb,
    const void* __restrict__ attr_emb, const int* __restrict__ flag) {
    const int isf = *flag;
    int idx = blockIdx.x * 256 + threadIdx.x;
    int n = idx >> 6, c = idx & 63;
    if (n >= NN) return;
    int ty = x_type[n];
    float tv = ldw(type_emb, ty * 64 + c, isf);
    x[n * CC + c] = tv;
    xbf[n * CC + c] = f2b(tv);
    int cnt = x_mask[n];
    float s = 0.f;
    for (int a = 0; a < cnt; ++a) s += ldw(attr_emb, x_attrs[n * AA + a] * 64 + c, isf);
    float av = s / (float)cnt;
    x[n * CC + 64 + c] = av;
    xbf[n * CC + 64 + c] = f2b(av);
}

// ---------------- CSR build ----------------
__global__ __launch_bounds__(256) void deg_kernel(int* __restrict__ cnt, const int* __restrict__ ei) {
    int e = blockIdx.x * 256 + threadIdx.x;
    if (e < EE) atomicAdd(&cnt[ei[EE + e]], 1);
}
__global__ __launch_bounds__(256) void scan1_kernel(int* __restrict__ cnt, int* __restrict__ btot) {
    __shared__ int s[256];
    int tid = threadIdx.x, i = blockIdx.x * 256 + tid;
    int v = (i < NN) ? cnt[i] : 0;
    s[tid] = v; __syncthreads();
    for (int off = 1; off < 256; off <<= 1) {
        int t = (tid >= off) ? s[tid - off] : 0; __syncthreads();
        s[tid] += t; __syncthreads();
    }
    if (i < NN) cnt[i] = s[tid] - v;
    if (tid == 255) btot[blockIdx.x] = s[255];
}
__global__ __launch_bounds__(256) void scan2_kernel(int* __restrict__ btot, int nb) {
    __shared__ int s[256];
    int tid = threadIdx.x;
    int v = (tid < nb) ? btot[tid] : 0;
    s[tid] = v; __syncthreads();
    for (int off = 1; off < 256; off <<= 1) {
        int t = (tid >= off) ? s[tid - off] : 0; __syncthreads();
        s[tid] += t; __syncthreads();
    }
    if (tid < nb) btot[tid] = s[tid] - v;
}
__global__ __launch_bounds__(256) void scan3_kernel(int* __restrict__ cnt, const int* __restrict__ btot) {
    int i = blockIdx.x * 256 + threadIdx.x;
    if (i < NN) cnt[i] += btot[blockIdx.x];
}
__global__ __launch_bounds__(256) void fill_kernel(uint* __restrict__ csr, int* __restrict__ cnt,
                                                   const int* __restrict__ ei, const int* __restrict__ ea) {
    int e = blockIdx.x * 256 + threadIdx.x;
    if (e >= EE) return;
    int d = ei[EE + e];
    int pos = atomicAdd(&cnt[d], 1);
    csr[pos] = (uint)ei[e] | ((uint)ea[e] << 16);
}

// ---------------- msg MFMA: block = 16-node tile, wave = 1 edge type ----------------
__global__ __launch_bounds__(256) void msg_mfma4(
    ushort* __restrict__ h4, const ushort* __restrict__ xbf, const ushort* __restrict__ wT) {
    int tid = threadIdx.x;
    int t = tid >> 6, l = tid & 63;
    int node0 = blockIdx.x * 16;
    int lr = l & 15, lk = (l >> 4) * 8;
    bf16x8 af[4];
#pragma unroll
    for (int ks = 0; ks < 4; ++ks)
        af[ks] = *(const bf16x8*)&xbf[(size_t)(node0 + lr) * CC + ks * 32 + lk];
#pragma unroll
    for (int ct = 0; ct < 8; ++ct) {
        fx4 acc = {0.f, 0.f, 0.f, 0.f};
#pragma unroll
        for (int ks = 0; ks < 4; ++ks) {
            bf16x8 bf = *(const bf16x8*)&wT[(size_t)(t * 128 + ct * 16 + lr) * 128 + ks * 32 + lk];
            acc = __builtin_amdgcn_mfma_f32_16x16x32_bf16(af[ks], bf, acc, 0, 0, 0);
        }
#pragma unroll
        for (int r = 0; r < 4; ++r) {
            int node = node0 + (l >> 4) * 4 + r;
            h4[((size_t)t * NN + node) * CC + ct * 16 + lr] = f2b(acc[r]);
        }
    }
}

// ---------------- gather: m[d] = sum h4[type][src] (wave per node) ----------------
__global__ __launch_bounds__(256) void gather_kernel(
    ushort* __restrict__ mbf, const ushort* __restrict__ h4,
    const uint* __restrict__ csr, const int* __restrict__ endp) {
    int w = threadIdx.x >> 6, l = threadIdx.x & 63;
    int node = blockIdx.x * 4 + w;
    int start = (node == 0) ? 0 : endp[node - 1];
    int end = endp[node];
    int c0 = l * 2;
    float s0 = 0.f, s1 = 0.f;
    for (int i = start; i < end; ++i) {
        uint pk = csr[i];
        uint src = pk & 0xFFFFu, t = pk >> 16;
        uint hv = *(const uint*)&h4[(((size_t)t * NN + src) << 7) + c0];
        s0 += b2f((ushort)(hv & 0xFFFFu));
        s1 += b2f((ushort)(hv >> 16));
    }
    *(uint*)&mbf[((size_t)node << 7) + c0] = (uint)f2b(s0) | ((uint)f2b(s1) << 16);
}

// ---------------- GRU MFMA: block = 16-node tile, wave = 2 col-tiles ----------------
__global__ __launch_bounds__(256) void gru_mfma(
    float* __restrict__ x, ushort* __restrict__ xbf, const ushort* __restrict__ mbf,
    const void* __restrict__ Wih, const void* __restrict__ Whh,
    const void* __restrict__ bih, const void* __restrict__ bhh,
    const int* __restrict__ flag) {
    const int isf = *flag;
    int tid = threadIdx.x;
    int w = tid >> 6, l = tid & 63;
    int node0 = blockIdx.x * 16;
    int lr = l & 15, lk = (l >> 4) * 8;
    bf16x8 mf[4], xf[4];
#pragma unroll
    for (int ks = 0; ks < 4; ++ks) {
        mf[ks] = *(const bf16x8*)&mbf[(size_t)(node0 + lr) * CC + ks * 32 + lk];
        xf[ks] = *(const bf16x8*)&xbf[(size_t)(node0 + lr) * CC + ks * 32 + lk];
    }
    __syncthreads();   // all waves' A-frags in regs before any wave writes x/xbf
#pragma unroll
    for (int cc = 0; cc < 2; ++cc) {
        int ct = w * 2 + cc;
        fx4 ai0 = {0,0,0,0}, ai1 = {0,0,0,0}, ai2 = {0,0,0,0};
        fx4 ah0 = {0,0,0,0}, ah1 = {0,0,0,0}, ah2 = {0,0,0,0};
        long ob0 = (long)(0 * 128 + ct * 16 + lr) * 128 + lk;
        long ob1 = (long)(1 * 128 + ct * 16 + lr) * 128 + lk;
        long ob2 = (long)(2 * 128 + ct * 16 + lr) * 128 + lk;
#pragma unroll
        for (int ks = 0; ks < 4; ++ks) {
            ai0 = __builtin_amdgcn_mfma_f32_16x16x32_bf16(mf[ks], wfrag(Wih, ob0 + ks * 32, isf), ai0, 0, 0, 0);
            ah0 = __builtin_amdgcn_mfma_f32_16x16x32_bf16(xf[ks], wfrag(Whh, ob0 + ks * 32, isf), ah0, 0, 0, 0);
            ai1 = __builtin_amdgcn_mfma_f32_16x16x32_bf16(mf[ks], wfrag(Wih, ob1 + ks * 32, isf), ai1, 0, 0, 0);
            ah1 = __builtin_amdgcn_mfma_f32_16x16x32_bf16(xf[ks], wfrag(Whh, ob1 + ks * 32, isf), ah1, 0, 0, 0);
            ai2 = __builtin_amdgcn_mfma_f32_16x16x32_bf16(mf[ks], wfrag(Wih, ob2 + ks * 32, isf), ai2, 0, 0, 0);
            ah2 = __builtin_amdgcn_mfma_f32_16x16x32_bf16(xf[ks], wfrag(Whh, ob2 + ks * 32, isf), ah2, 0, 0, 0);
        }
        int o0 = ct * 16 + lr;
        float bi0 = ldw(bih, o0, isf),       bh0 = ldw(bhh, o0, isf);
        float bi1 = ldw(bih, 128 + o0, isf), bh1 = ldw(bhh, 128 + o0, isf);
        float bi2 = ldw(bih, 256 + o0, isf), bh2 = ldw(bhh, 256 + o0, isf);
#pragma unroll
        for (int r = 0; r < 4; ++r) {
            int node = node0 + (l >> 4) * 4 + r;
            float rg = sigm(ai0[r] + bi0 + ah0[r] + bh0);
            float zg = sigm(ai1[r] + bi1 + ah1[r] + bh1);
            float ny = ai2[r] + bi2 + rg * (ah2[r] + bh2);
            float ng = 2.f * sigm(2.f * ny) - 1.f;   // tanh
            size_t xi = (size_t)node * CC + o0;
            float xo = x[xi];
            float xn = (1.f - zg) * ng + zg * xo;
            x[xi] = xn;
            xbf[xi] = f2b(xn);
        }
    }
}

// ---------------- aggregation ----------------
__global__ __launch_bounds__(256) void agg_kernel(
    float* __restrict__ sums, float* __restrict__ cnt, const float* __restrict__ x,
    const int* __restrict__ batch, const int* __restrict__ x_type) {
    int idx = blockIdx.x * 256 + threadIdx.x;
    int n = idx >> 7, c = idx & 127;
    int seg = batch[n] * TT + x_type[n];
    atomicAdd(&sums[seg * CC + c], x[idx]);
    if (c == 0) atomicAdd(&cnt[seg], 1.0f);
}

// ---------------- final ----------------
__global__ __launch_bounds__(256) void final_kernel(
    void* __restrict__ out, const float* __restrict__ sums, const float* __restrict__ cnt,
    const void* __restrict__ w_attn, const void* __restrict__ b_attn,
    const void* __restrict__ W_enc, const void* __restrict__ b_enc,
    const void* __restrict__ W_dec, const void* __restrict__ b_dec,
    const int* __restrict__ flag) {
    const int isf = *flag;
    __shared__ float agg_s[TT][CC];
    __shared__ float wpart[TT][8];
    __shared__ float attn_s[TT];
    __shared__ float enc_s[2][ENC];
    int b = blockIdx.x, tid = threadIdx.x;
#pragma unroll
    for (int q = 0; q < 8; ++q) {
        int idx = tid + q * 256;
        int t = idx >> 7, c = idx & 127;
        float cv = cnt[b * TT + t];
        agg_s[t][c] = cv > 0.f ? sums[(b * TT + t) * CC + c] / cv : 0.f;
    }
    __syncthreads();
    if (tid < 128) {
        int t = tid >> 3, p = tid & 7;
        float acc = 0.f;
        for (int i = 0; i < 16; ++i) acc += agg_s[t][p * 16 + i] * ldw(w_attn, p * 16 + i, isf);
        wpart[t][p] = acc;
    }
    __syncthreads();
    if (tid < 16) {
        float acc = ldw(b_attn, 0, isf);
        for (int p = 0; p < 8; ++p) acc += wpart[tid][p];
        attn_s[tid] = acc;
    }
    __syncthreads();
    if (tid == 0) {
        float mx = attn_s[0];
        for (int t = 1; t < TT; ++t) mx = fmaxf(mx, attn_s[t]);
        float ssum = 0.f, ex[TT];
        for (int t = 0; t < TT; ++t) { ex[t] = expf(attn_s[t] - mx); ssum += ex[t]; }
        for (int t = 0; t < TT; ++t) attn_s[t] = ex[t] / ssum;
    }
    __syncthreads();
#pragma unroll
    for (int q = 0; q < 8; ++q) {
        int idx = tid + q * 256;
        int t = idx >> 7, c = idx & 127;
        agg_s[t][c] *= attn_s[t];
    }
    __syncthreads();
    {
        int half = tid >> 7, j = tid & 127;
        const float* flat = &agg_s[0][0];
        float acc = 0.f;
        for (int i = half * 1024; i < half * 1024 + 1024; ++i)
            acc += flat[i] * ldw(W_enc, i * ENC + j, isf);
        enc_s[half][j] = acc;
    }
    __syncthreads();
    if (tid < 128) enc_s[0][tid] = enc_s[0][tid] + enc_s[1][tid] + ldw(b_enc, tid, isf);
    __syncthreads();
    if (tid < NCLS) {
        float acc = ldw(b_dec, tid, isf);
        for (int j = 0; j < ENC; ++j) acc += enc_s[0][j] * ldw(W_dec, j * NCLS + tid, isf);
        int oi = b * NCLS + tid;
        if (isf) ((float*)out)[oi] = acc;
        else ((ushort*)out)[oi] = f2b(acc);
    }
}

extern "C" void kernel_launch(void* const* d_in, const int* in_sizes, int n_in,
                              void* d_out, int out_size, void* d_ws, size_t ws_size,
                              hipStream_t stream) {
    const int* x_type      = (const int*)d_in[0];
    const int* x_attrs     = (const int*)d_in[1];
    const int* x_mask      = (const int*)d_in[2];
    const int* edge_index  = (const int*)d_in[3];
    const int* edge_attr   = (const int*)d_in[4];
    const int* batch       = (const int*)d_in[6];
    const void* type_emb   = d_in[7];
    const void* attr_emb   = d_in[8];
    const void* W_msg      = d_in[9];
    const void* W_ih       = d_in[10];
    const void* W_hh       = d_in[11];
    const void* b_ih       = d_in[12];
    const void* b_hh       = d_in[13];
    const void* w_attn     = d_in[14];
    const void* b_attn     = d_in[15];
    const void* W_enc      = d_in[16];
    const void* b_enc      = d_in[17];
    const void* W_dec      = d_in[18];
    const void* b_dec      = d_in[19];

    char* p = (char*)d_ws;
    float*  x    = (float*)p;            p += (size_t)NN * CC * 4;       // 25.6 MB
    ushort* xbf  = (ushort*)p;           p += (size_t)NN * CC * 2;       // 12.8 MB
    ushort* mbf  = (ushort*)p;           p += (size_t)NN * CC * 2;       // 12.8 MB
    ushort* h4   = (ushort*)p;           p += (size_t)4 * NN * CC * 2;   // 51.2 MB
    ushort* wT   = (ushort*)p;           p += (size_t)16 * 128 * 128 * 2;
    float*  sums = (float*)p;            p += (size_t)BB * TT * CC * 4;
    float*  cnta = (float*)p;            p += (size_t)BB * TT * 4;
    uint*   csr  = (uint*)p;             p += (size_t)EE * 4;
    int*    cptr = (int*)p;              p += (size_t)NN * 4;
    int*    btot = (int*)p;              p += 256 * 4;
    int*    flag = (int*)p;

    sniff_kernel<<<1, 1, 0, stream>>>(flag, W_enc);
    wmsgT_kernel<<<1024, 256, 0, stream>>>(wT, W_msg, flag);
    embed_kernel<<<(NN * 64) / 256, 256, 0, stream>>>(x, xbf, x_type, x_attrs, x_mask,
                                                      type_emb, attr_emb, flag);

    // ---- CSR build ----
    const int NB = (NN + 255) / 256;
    hipMemsetAsync(cptr, 0, (size_t)NN * sizeof(int), stream);
    deg_kernel<<<(EE + 255) / 256, 256, 0, stream>>>(cptr, edge_index);
    scan1_kernel<<<NB, 256, 0, stream>>>(cptr, btot);
    scan2_kernel<<<1, 256, 0, stream>>>(btot, NB);
    scan3_kernel<<<NB, 256, 0, stream>>>(cptr, btot);
    fill_kernel<<<(EE + 255) / 256, 256, 0, stream>>>(csr, cptr, edge_index, edge_attr);

    const int tile_grid = NN / 16;   // 3125
    for (int l = 0; l < LL; ++l) {
        msg_mfma4<<<tile_grid, 256, 0, stream>>>(h4, xbf, wT + (size_t)l * 4 * 128 * 128);
        gather_kernel<<<NN / 4, 256, 0, stream>>>(mbf, h4, csr, cptr);
        gru_mfma<<<tile_grid, 256, 0, stream>>>(x, xbf, mbf, W_ih, W_hh, b_ih, b_hh, flag);
    }

    hipMemsetAsync(sums, 0, (size_t)(BB * TT * CC + BB * TT) * sizeof(float), stream);
    agg_kernel<<<(NN * CC) / 256, 256, 0, stream>>>(sums, cnta, x, batch, x_type);
    final_kernel<<<BB, 256, 0, stream>>>(d_out, sums, cnta, w_attn, b_attn,
                                         W_enc, b_enc, W_dec, b_dec, flag);
}

// Round 8
// 937.169 us; speedup vs baseline: 4.4681x; 1.4613x over previous
//
#include <hip/hip_runtime.h>
#include <hip/hip_bf16.h>

#define NN 50000
#define EE 600000
#define AA 8
#define CC 128
#define TT 16
#define TE 4
#define LL 4
#define BB 256
#define ENC 128
#define NCLS 10

typedef __attribute__((ext_vector_type(8))) short bf16x8;
typedef __attribute__((ext_vector_type(4))) float fx4;

__device__ __forceinline__ float b2f(ushort u) {
    union { float f; uint32_t i; } v; v.i = ((uint32_t)u) << 16; return v.f;
}
__device__ __forceinline__ ushort f2b(float f) {
    union { float f; uint32_t i; } v; v.f = f;
    uint32_t x = v.i;
    x += 0x7FFFu + ((x >> 16) & 1u);
    return (ushort)(x >> 16);
}
__device__ __forceinline__ float ldw(const void* p, long i, int isf) {
    return isf ? ((const float*)p)[i] : b2f(((const ushort*)p)[i]);
}
__device__ __forceinline__ float sigm(float t) { return 1.f / (1.f + __expf(-t)); }

// ---------------- dtype sniff ----------------
__global__ void sniff_kernel(int* flag, const void* W_enc_raw) {
    const ushort* u = (const ushort*)W_enc_raw;
    int good = 0;
    for (int i = 0; i < 256; ++i) {
        ushort v = u[i];
        int ex = (v >> 7) & 0xFF;
        if (v == 0 || (ex >= 100 && ex <= 126)) ++good;
    }
    *flag = (good >= 230) ? 0 : 1;   // 0 = bf16, 1 = f32
}

// ---------------- transpose all W_msg into wT[l*4+t][d][c] (bf16) ----------------
__global__ __launch_bounds__(256) void wmsgT_kernel(ushort* __restrict__ wT,
                                                    const void* __restrict__ W,
                                                    const int* __restrict__ flag) {
    const int isf = *flag;
    int idx = blockIdx.x * 256 + threadIdx.x;
    int lt = idx >> 14, rem = idx & 16383, d = rem >> 7, c = rem & 127;
    long src = ((long)lt << 14) + c * 128 + d;
    wT[idx] = isf ? f2b(((const float*)W)[src]) : ((const ushort*)W)[src];
}

// ---------------- convert Wih||Whh -> bf16 (same layout), biases -> f32 ----------------
// wgb[0..49151] = Wih (row-major [384][128]); wgb[49152..98303] = Whh
__global__ __launch_bounds__(256) void wgru_kernel(ushort* __restrict__ wgb,
                                                   const void* __restrict__ Wih,
                                                   const void* __restrict__ Whh,
                                                   const int* __restrict__ flag) {
    const int isf = *flag;
    int idx = blockIdx.x * 256 + threadIdx.x;     // 0 .. 98303
    if (idx >= 98304) return;
    int ih = (idx < 49152);
    int off = ih ? idx : idx - 49152;
    wgb[idx] = f2b(ldw(ih ? Wih : Whh, off, isf));
}
__global__ __launch_bounds__(256) void bconv_kernel(float* __restrict__ bbias,
                                                    const void* __restrict__ bih,
                                                    const void* __restrict__ bhh,
                                                    const int* __restrict__ flag) {
    const int isf = *flag;
    int i = blockIdx.x * 256 + threadIdx.x;       // 0..767
    if (i < 384) bbias[i] = ldw(bih, i, isf);
    else if (i < 768) bbias[i] = ldw(bhh, i - 384, isf);
}

// ---------------- embed: writes f32 x and bf16 mirror xbf ----------------
__global__ __launch_bounds__(256) void embed_kernel(
    float* __restrict__ x, ushort* __restrict__ xbf,
    const int* __restrict__ x_type, const int* __restrict__ x_attrs,
    const int* __restrict__ x_mask, const void* __restrict__ type_emb,
    const void* __restrict__ attr_emb, const int* __restrict__ flag) {
    const int isf = *flag;
    int idx = blockIdx.x * 256 + threadIdx.x;
    int n = idx >> 6, c = idx & 63;
    if (n >= NN) return;
    int ty = x_type[n];
    float tv = ldw(type_emb, ty * 64 + c, isf);
    x[n * CC + c] = tv;
    xbf[n * CC + c] = f2b(tv);
    int cnt = x_mask[n];
    float s = 0.f;
    for (int a = 0; a < cnt; ++a) s += ldw(attr_emb, x_attrs[n * AA + a] * 64 + c, isf);
    float av = s / (float)cnt;
    x[n * CC + 64 + c] = av;
    xbf[n * CC + 64 + c] = f2b(av);
}

// ---------------- CSR build ----------------
__global__ __launch_bounds__(256) void deg_kernel(int* __restrict__ cnt, const int* __restrict__ ei) {
    int e = blockIdx.x * 256 + threadIdx.x;
    if (e < EE) atomicAdd(&cnt[ei[EE + e]], 1);
}
__global__ __launch_bounds__(256) void scan1_kernel(int* __restrict__ cnt, int* __restrict__ btot) {
    __shared__ int s[256];
    int tid = threadIdx.x, i = blockIdx.x * 256 + tid;
    int v = (i < NN) ? cnt[i] : 0;
    s[tid] = v; __syncthreads();
    for (int off = 1; off < 256; off <<= 1) {
        int t = (tid >= off) ? s[tid - off] : 0; __syncthreads();
        s[tid] += t; __syncthreads();
    }
    if (i < NN) cnt[i] = s[tid] - v;
    if (tid == 255) btot[blockIdx.x] = s[255];
}
__global__ __launch_bounds__(256) void scan2_kernel(int* __restrict__ btot, int nb) {
    __shared__ int s[256];
    int tid = threadIdx.x;
    int v = (tid < nb) ? btot[tid] : 0;
    s[tid] = v; __syncthreads();
    for (int off = 1; off < 256; off <<= 1) {
        int t = (tid >= off) ? s[tid - off] : 0; __syncthreads();
        s[tid] += t; __syncthreads();
    }
    if (tid < nb) btot[tid] = s[tid] - v;
}
__global__ __launch_bounds__(256) void scan3_kernel(int* __restrict__ cnt, const int* __restrict__ btot) {
    int i = blockIdx.x * 256 + threadIdx.x;
    if (i < NN) cnt[i] += btot[blockIdx.x];
}
__global__ __launch_bounds__(256) void fill_kernel(uint* __restrict__ csr, int* __restrict__ cnt,
                                                   const int* __restrict__ ei, const int* __restrict__ ea) {
    int e = blockIdx.x * 256 + threadIdx.x;
    if (e >= EE) return;
    int d = ei[EE + e];
    int pos = atomicAdd(&cnt[d], 1);
    csr[pos] = (uint)ei[e] | ((uint)ea[e] << 16);
}

// ---------------- msg MFMA: block = 32-node tile, wave = 1 edge type, 2 row-tiles ----------------
__global__ __launch_bounds__(256) void msg_mfma4(
    ushort* __restrict__ h4, const ushort* __restrict__ xbf, const ushort* __restrict__ wT) {
    int tid = threadIdx.x;
    int t = tid >> 6, l = tid & 63;
    int node0 = blockIdx.x * 32;
    int lr = l & 15, lk = (l >> 4) * 8;
    bf16x8 af[2][4];
#pragma unroll
    for (int rt = 0; rt < 2; ++rt)
#pragma unroll
        for (int ks = 0; ks < 4; ++ks)
            af[rt][ks] = *(const bf16x8*)&xbf[(size_t)(node0 + rt * 16 + lr) * CC + ks * 32 + lk];
#pragma unroll
    for (int ct = 0; ct < 8; ++ct) {
        bf16x8 bfr[4];
#pragma unroll
        for (int ks = 0; ks < 4; ++ks)
            bfr[ks] = *(const bf16x8*)&wT[(size_t)(t * 128 + ct * 16 + lr) * 128 + ks * 32 + lk];
        fx4 acc0 = {0.f, 0.f, 0.f, 0.f}, acc1 = {0.f, 0.f, 0.f, 0.f};
#pragma unroll
        for (int ks = 0; ks < 4; ++ks) {
            acc0 = __builtin_amdgcn_mfma_f32_16x16x32_bf16(af[0][ks], bfr[ks], acc0, 0, 0, 0);
            acc1 = __builtin_amdgcn_mfma_f32_16x16x32_bf16(af[1][ks], bfr[ks], acc1, 0, 0, 0);
        }
#pragma unroll
        for (int r = 0; r < 4; ++r) {
            int n0 = node0 + (l >> 4) * 4 + r;
            int n1 = n0 + 16;
            if (n0 < NN) h4[((size_t)t * NN + n0) * CC + ct * 16 + lr] = f2b(acc0[r]);
            if (n1 < NN) h4[((size_t)t * NN + n1) * CC + ct * 16 + lr] = f2b(acc1[r]);
        }
    }
}

// ---------------- gather: m[d] = sum h4[type][src] (wave per node) ----------------
__global__ __launch_bounds__(256) void gather_kernel(
    ushort* __restrict__ mbf, const ushort* __restrict__ h4,
    const uint* __restrict__ csr, const int* __restrict__ endp) {
    int w = threadIdx.x >> 6, l = threadIdx.x & 63;
    int node = blockIdx.x * 4 + w;
    int start = (node == 0) ? 0 : endp[node - 1];
    int end = endp[node];
    int c0 = l * 2;
    float s0 = 0.f, s1 = 0.f;
    for (int i = start; i < end; ++i) {
        uint pk = csr[i];
        uint src = pk & 0xFFFFu, t = pk >> 16;
        uint hv = *(const uint*)&h4[(((size_t)t * NN + src) << 7) + c0];
        s0 += b2f((ushort)(hv & 0xFFFFu));
        s1 += b2f((ushort)(hv >> 16));
    }
    *(uint*)&mbf[((size_t)node << 7) + c0] = (uint)f2b(s0) | ((uint)f2b(s1) << 16);
}

// ---------------- GRU MFMA: block = 32-node tile, wave = 2 col-tiles, 2 row-tiles ----------------
// wgb: [0,49152) = Wih bf16 row-major [384][128]; [49152,98304) = Whh
__global__ __launch_bounds__(256) void gru_mfma(
    float* __restrict__ x, ushort* __restrict__ xbf, const ushort* __restrict__ mbf,
    const ushort* __restrict__ wgb, const float* __restrict__ bbias) {
    int tid = threadIdx.x;
    int w = tid >> 6, l = tid & 63;
    int node0 = blockIdx.x * 32;
    int lr = l & 15, lk = (l >> 4) * 8;
    bf16x8 mf[2][4], xf[2][4];
#pragma unroll
    for (int rt = 0; rt < 2; ++rt)
#pragma unroll
        for (int ks = 0; ks < 4; ++ks) {
            size_t ro = (size_t)(node0 + rt * 16 + lr) * CC + ks * 32 + lk;
            mf[rt][ks] = *(const bf16x8*)&mbf[ro];
            xf[rt][ks] = *(const bf16x8*)&xbf[ro];
        }
    __syncthreads();   // all waves' A-frags in regs before any wave writes x/xbf
#pragma unroll
    for (int cc = 0; cc < 2; ++cc) {
        int ct = w * 2 + cc;
        int row0 = ct * 16 + lr;                   // output col within gate
        fx4 ai[3][2], ah[3][2];
#pragma unroll
        for (int s = 0; s < 3; ++s)
#pragma unroll
            for (int rt = 0; rt < 2; ++rt) { ai[s][rt] = (fx4){0,0,0,0}; ah[s][rt] = (fx4){0,0,0,0}; }
#pragma unroll
        for (int ks = 0; ks < 4; ++ks) {
            int ko = ks * 32 + lk;
            bf16x8 bI[3], bH[3];
#pragma unroll
            for (int s = 0; s < 3; ++s) {
                bI[s] = *(const bf16x8*)&wgb[(size_t)(s * 128 + row0) * 128 + ko];
                bH[s] = *(const bf16x8*)&wgb[49152 + (size_t)(s * 128 + row0) * 128 + ko];
            }
#pragma unroll
            for (int s = 0; s < 3; ++s)
#pragma unroll
                for (int rt = 0; rt < 2; ++rt) {
                    ai[s][rt] = __builtin_amdgcn_mfma_f32_16x16x32_bf16(mf[rt][ks], bI[s], ai[s][rt], 0, 0, 0);
                    ah[s][rt] = __builtin_amdgcn_mfma_f32_16x16x32_bf16(xf[rt][ks], bH[s], ah[s][rt], 0, 0, 0);
                }
        }
        float bi0 = bbias[row0],        bh0 = bbias[384 + row0];
        float bi1 = bbias[128 + row0],  bh1 = bbias[512 + row0];
        float bi2 = bbias[256 + row0],  bh2 = bbias[640 + row0];
#pragma unroll
        for (int rt = 0; rt < 2; ++rt)
#pragma unroll
            for (int r = 0; r < 4; ++r) {
                int node = node0 + rt * 16 + (l >> 4) * 4 + r;
                if (node >= NN) continue;
                float rg = sigm(ai[0][rt][r] + bi0 + ah[0][rt][r] + bh0);
                float zg = sigm(ai[1][rt][r] + bi1 + ah[1][rt][r] + bh1);
                float ny = ai[2][rt][r] + bi2 + rg * (ah[2][rt][r] + bh2);
                float ng = 2.f * sigm(2.f * ny) - 1.f;   // tanh
                size_t xi = (size_t)node * CC + row0;
                float xo = x[xi];
                float xn = (1.f - zg) * ng + zg * xo;
                x[xi] = xn;
                xbf[xi] = f2b(xn);
            }
    }
}

// ---------------- aggregation ----------------
__global__ __launch_bounds__(256) void agg_kernel(
    float* __restrict__ sums, float* __restrict__ cnt, const float* __restrict__ x,
    const int* __restrict__ batch, const int* __restrict__ x_type) {
    int idx = blockIdx.x * 256 + threadIdx.x;
    int n = idx >> 7, c = idx & 127;
    int seg = batch[n] * TT + x_type[n];
    atomicAdd(&sums[seg * CC + c], x[idx]);
    if (c == 0) atomicAdd(&cnt[seg], 1.0f);
}

// ---------------- final ----------------
__global__ __launch_bounds__(256) void final_kernel(
    void* __restrict__ out, const float* __restrict__ sums, const float* __restrict__ cnt,
    const void* __restrict__ w_attn, const void* __restrict__ b_attn,
    const void* __restrict__ W_enc, const void* __restrict__ b_enc,
    const void* __restrict__ W_dec, const void* __restrict__ b_dec,
    const int* __restrict__ flag) {
    const int isf = *flag;
    __shared__ float agg_s[TT][CC];
    __shared__ float wpart[TT][8];
    __shared__ float attn_s[TT];
    __shared__ float enc_s[2][ENC];
    int b = blockIdx.x, tid = threadIdx.x;
#pragma unroll
    for (int q = 0; q < 8; ++q) {
        int idx = tid + q * 256;
        int t = idx >> 7, c = idx & 127;
        float cv = cnt[b * TT + t];
        agg_s[t][c] = cv > 0.f ? sums[(b * TT + t) * CC + c] / cv : 0.f;
    }
    __syncthreads();
    if (tid < 128) {
        int t = tid >> 3, p = tid & 7;
        float acc = 0.f;
        for (int i = 0; i < 16; ++i) acc += agg_s[t][p * 16 + i] * ldw(w_attn, p * 16 + i, isf);
        wpart[t][p] = acc;
    }
    __syncthreads();
    if (tid < 16) {
        float acc = ldw(b_attn, 0, isf);
        for (int p = 0; p < 8; ++p) acc += wpart[tid][p];
        attn_s[tid] = acc;
    }
    __syncthreads();
    if (tid == 0) {
        float mx = attn_s[0];
        for (int t = 1; t < TT; ++t) mx = fmaxf(mx, attn_s[t]);
        float ssum = 0.f, ex[TT];
        for (int t = 0; t < TT; ++t) { ex[t] = expf(attn_s[t] - mx); ssum += ex[t]; }
        for (int t = 0; t < TT; ++t) attn_s[t] = ex[t] / ssum;
    }
    __syncthreads();
#pragma unroll
    for (int q = 0; q < 8; ++q) {
        int idx = tid + q * 256;
        int t = idx >> 7, c = idx & 127;
        agg_s[t][c] *= attn_s[t];
    }
    __syncthreads();
    {
        int half = tid >> 7, j = tid & 127;
        const float* flat = &agg_s[0][0];
        float acc = 0.f;
        for (int i = half * 1024; i < half * 1024 + 1024; ++i)
            acc += flat[i] * ldw(W_enc, i * ENC + j, isf);
        enc_s[half][j] = acc;
    }
    __syncthreads();
    if (tid < 128) enc_s[0][tid] = enc_s[0][tid] + enc_s[1][tid] + ldw(b_enc, tid, isf);
    __syncthreads();
    if (tid < NCLS) {
        float acc = ldw(b_dec, tid, isf);
        for (int j = 0; j < ENC; ++j) acc += enc_s[0][j] * ldw(W_dec, j * NCLS + tid, isf);
        int oi = b * NCLS + tid;
        if (isf) ((float*)out)[oi] = acc;
        else ((ushort*)out)[oi] = f2b(acc);
    }
}

extern "C" void kernel_launch(void* const* d_in, const int* in_sizes, int n_in,
                              void* d_out, int out_size, void* d_ws, size_t ws_size,
                              hipStream_t stream) {
    const int* x_type      = (const int*)d_in[0];
    const int* x_attrs     = (const int*)d_in[1];
    const int* x_mask      = (const int*)d_in[2];
    const int* edge_index  = (const int*)d_in[3];
    const int* edge_attr   = (const int*)d_in[4];
    const int* batch       = (const int*)d_in[6];
    const void* type_emb   = d_in[7];
    const void* attr_emb   = d_in[8];
    const void* W_msg      = d_in[9];
    const void* W_ih       = d_in[10];
    const void* W_hh       = d_in[11];
    const void* b_ih       = d_in[12];
    const void* b_hh       = d_in[13];
    const void* w_attn     = d_in[14];
    const void* b_attn     = d_in[15];
    const void* W_enc      = d_in[16];
    const void* b_enc      = d_in[17];
    const void* W_dec      = d_in[18];
    const void* b_dec      = d_in[19];

    char* p = (char*)d_ws;
    float*  x    = (float*)p;            p += (size_t)NN * CC * 4;       // 25.6 MB
    ushort* xbf  = (ushort*)p;           p += (size_t)NN * CC * 2;       // 12.8 MB
    ushort* mbf  = (ushort*)p;           p += (size_t)NN * CC * 2;       // 12.8 MB
    ushort* h4   = (ushort*)p;           p += (size_t)4 * NN * CC * 2;   // 51.2 MB
    ushort* wT   = (ushort*)p;           p += (size_t)16 * 128 * 128 * 2;
    ushort* wgb  = (ushort*)p;           p += (size_t)2 * 384 * 128 * 2; // 192 KB
    float*  bbias= (float*)p;            p += 768 * 4;
    float*  sums = (float*)p;            p += (size_t)BB * TT * CC * 4;
    float*  cnta = (float*)p;            p += (size_t)BB * TT * 4;
    uint*   csr  = (uint*)p;             p += (size_t)EE * 4;
    int*    cptr = (int*)p;              p += (size_t)NN * 4;
    int*    btot = (int*)p;              p += 256 * 4;
    int*    flag = (int*)p;

    sniff_kernel<<<1, 1, 0, stream>>>(flag, W_enc);
    wmsgT_kernel<<<1024, 256, 0, stream>>>(wT, W_msg, flag);
    wgru_kernel<<<384, 256, 0, stream>>>(wgb, W_ih, W_hh, flag);
    bconv_kernel<<<3, 256, 0, stream>>>(bbias, b_ih, b_hh, flag);
    embed_kernel<<<(NN * 64) / 256, 256, 0, stream>>>(x, xbf, x_type, x_attrs, x_mask,
                                                      type_emb, attr_emb, flag);

    // ---- CSR build ----
    const int NB = (NN + 255) / 256;
    hipMemsetAsync(cptr, 0, (size_t)NN * sizeof(int), stream);
    deg_kernel<<<(EE + 255) / 256, 256, 0, stream>>>(cptr, edge_index);
    scan1_kernel<<<NB, 256, 0, stream>>>(cptr, btot);
    scan2_kernel<<<1, 256, 0, stream>>>(btot, NB);
    scan3_kernel<<<NB, 256, 0, stream>>>(cptr, btot);
    fill_kernel<<<(EE + 255) / 256, 256, 0, stream>>>(csr, cptr, edge_index, edge_attr);

    const int tile_grid = (NN + 31) / 32;   // 1563
    for (int l = 0; l < LL; ++l) {
        msg_mfma4<<<tile_grid, 256, 0, stream>>>(h4, xbf, wT + (size_t)l * 4 * 128 * 128);
        gather_kernel<<<NN / 4, 256, 0, stream>>>(mbf, h4, csr, cptr);
        gru_mfma<<<tile_grid, 256, 0, stream>>>(x, xbf, mbf, wgb, bbias);
    }

    hipMemsetAsync(sums, 0, (size_t)(BB * TT * CC + BB * TT) * sizeof(float), stream);
    agg_kernel<<<(NN * CC) / 256, 256, 0, stream>>>(sums, cnta, x, batch, x_type);
    final_kernel<<<BB, 256, 0, stream>>>(d_out, sums, cnta, w_attn, b_attn,
                                         W_enc, b_enc, W_dec, b_dec, flag);
}

// Round 9
// 850.447 us; speedup vs baseline: 4.9237x; 1.1020x over previous
//
#include <hip/hip_runtime.h>
#include <hip/hip_bf16.h>

#define NN 50000
#define EE 600000
#define AA 8
#define CC 128
#define TT 16
#define TE 4
#define LL 4
#define BB 256
#define ENC 128
#define NCLS 10

typedef __attribute__((ext_vector_type(8))) short bf16x8;
typedef __attribute__((ext_vector_type(4))) float fx4;

__device__ __forceinline__ float b2f(ushort u) {
    union { float f; uint32_t i; } v; v.i = ((uint32_t)u) << 16; return v.f;
}
__device__ __forceinline__ ushort f2b(float f) {
    union { float f; uint32_t i; } v; v.f = f;
    uint32_t x = v.i;
    x += 0x7FFFu + ((x >> 16) & 1u);
    return (ushort)(x >> 16);
}
__device__ __forceinline__ float ldw(const void* p, long i, int isf) {
    return isf ? ((const float*)p)[i] : b2f(((const ushort*)p)[i]);
}
__device__ __forceinline__ float sigm(float t) { return 1.f / (1.f + __expf(-t)); }

// ---------------- dtype sniff ----------------
__global__ void sniff_kernel(int* flag, const void* W_enc_raw) {
    const ushort* u = (const ushort*)W_enc_raw;
    int good = 0;
    for (int i = 0; i < 256; ++i) {
        ushort v = u[i];
        int ex = (v >> 7) & 0xFF;
        if (v == 0 || (ex >= 100 && ex <= 126)) ++good;
    }
    *flag = (good >= 230) ? 0 : 1;   // 0 = bf16, 1 = f32
}

// ---------------- transpose all W_msg into wT[l*4+t][d][c] (bf16) ----------------
__global__ __launch_bounds__(256) void wmsgT_kernel(ushort* __restrict__ wT,
                                                    const void* __restrict__ W,
                                                    const int* __restrict__ flag) {
    const int isf = *flag;
    int idx = blockIdx.x * 256 + threadIdx.x;
    int lt = idx >> 14, rem = idx & 16383, d = rem >> 7, c = rem & 127;
    long src = ((long)lt << 14) + c * 128 + d;
    wT[idx] = isf ? f2b(((const float*)W)[src]) : ((const ushort*)W)[src];
}

// ---------------- Wih||Whh -> bf16 ----------------
__global__ __launch_bounds__(256) void wgru_kernel(ushort* __restrict__ wgb,
                                                   const void* __restrict__ Wih,
                                                   const void* __restrict__ Whh,
                                                   const int* __restrict__ flag) {
    const int isf = *flag;
    int idx = blockIdx.x * 256 + threadIdx.x;     // 0 .. 98303
    if (idx >= 98304) return;
    int ih = (idx < 49152);
    int off = ih ? idx : idx - 49152;
    wgb[idx] = f2b(ldw(ih ? Wih : Whh, off, isf));
}

// ---------------- W_enc -> bf16 transposed [ENC][2048] ----------------
__global__ __launch_bounds__(256) void wencT_kernel(ushort* __restrict__ wencT,
                                                    const void* __restrict__ W_enc,
                                                    const int* __restrict__ flag) {
    const int isf = *flag;
    int idx = blockIdx.x * 256 + threadIdx.x;     // 0 .. 262143
    int j = idx >> 11, k = idx & 2047;            // wencT[j][k] = W_enc[k][j]
    wencT[idx] = f2b(ldw(W_enc, (long)k * ENC + j, isf));
}

// ---------------- small params -> f32 scratch ----------------
// layout: 0 bih(384) | 384 bhh(384) | 768 b_enc(128) | 896 w_attn(128)
//         1024 b_dec(10) | 1034 b_attn(1) | 1040 W_dec(1280) | total 2320
__global__ __launch_bounds__(256) void bconv_kernel(float* __restrict__ cvt,
                                                    const void* __restrict__ bih, const void* __restrict__ bhh,
                                                    const void* __restrict__ b_enc, const void* __restrict__ w_attn,
                                                    const void* __restrict__ b_dec, const void* __restrict__ b_attn,
                                                    const void* __restrict__ W_dec,
                                                    const int* __restrict__ flag) {
    const int isf = *flag;
    int i = blockIdx.x * 256 + threadIdx.x;
    if (i < 384) cvt[i] = ldw(bih, i, isf);
    else if (i < 768) cvt[i] = ldw(bhh, i - 384, isf);
    else if (i < 896) cvt[i] = ldw(b_enc, i - 768, isf);
    else if (i < 1024) cvt[i] = ldw(w_attn, i - 896, isf);
    else if (i < 1034) cvt[i] = ldw(b_dec, i - 1024, isf);
    else if (i == 1034) cvt[i] = ldw(b_attn, 0, isf);
    else if (i >= 1040 && i < 2320) cvt[i] = ldw(W_dec, i - 1040, isf);
}

// ---------------- embed: writes f32 x and bf16 mirror xbf ----------------
__global__ __launch_bounds__(256) void embed_kernel(
    float* __restrict__ x, ushort* __restrict__ xbf,
    const int* __restrict__ x_type, const int* __restrict__ x_attrs,
    const int* __restrict__ x_mask, const void* __restrict__ type_emb,
    const void* __restrict__ attr_emb, const int* __restrict__ flag) {
    const int isf = *flag;
    int idx = blockIdx.x * 256 + threadIdx.x;
    int n = idx >> 6, c = idx & 63;
    if (n >= NN) return;
    int ty = x_type[n];
    float tv = ldw(type_emb, ty * 64 + c, isf);
    x[n * CC + c] = tv;
    xbf[n * CC + c] = f2b(tv);
    int cnt = x_mask[n];
    float s = 0.f;
    for (int a = 0; a < cnt; ++a) s += ldw(attr_emb, x_attrs[n * AA + a] * 64 + c, isf);
    float av = s / (float)cnt;
    x[n * CC + 64 + c] = av;
    xbf[n * CC + 64 + c] = f2b(av);
}

// ---------------- CSR build ----------------
__global__ __launch_bounds__(256) void deg_kernel(int* __restrict__ cnt, const int* __restrict__ ei) {
    int e = blockIdx.x * 256 + threadIdx.x;
    if (e < EE) atomicAdd(&cnt[ei[EE + e]], 1);
}
__global__ __launch_bounds__(256) void scan1_kernel(int* __restrict__ cnt, int* __restrict__ btot) {
    __shared__ int s[256];
    int tid = threadIdx.x, i = blockIdx.x * 256 + tid;
    int v = (i < NN) ? cnt[i] : 0;
    s[tid] = v; __syncthreads();
    for (int off = 1; off < 256; off <<= 1) {
        int t = (tid >= off) ? s[tid - off] : 0; __syncthreads();
        s[tid] += t; __syncthreads();
    }
    if (i < NN) cnt[i] = s[tid] - v;
    if (tid == 255) btot[blockIdx.x] = s[255];
}
__global__ __launch_bounds__(256) void scan2_kernel(int* __restrict__ btot, int nb) {
    __shared__ int s[256];
    int tid = threadIdx.x;
    int v = (tid < nb) ? btot[tid] : 0;
    s[tid] = v; __syncthreads();
    for (int off = 1; off < 256; off <<= 1) {
        int t = (tid >= off) ? s[tid - off] : 0; __syncthreads();
        s[tid] += t; __syncthreads();
    }
    if (tid < nb) btot[tid] = s[tid] - v;
}
__global__ __launch_bounds__(256) void scan3_kernel(int* __restrict__ cnt, const int* __restrict__ btot) {
    int i = blockIdx.x * 256 + threadIdx.x;
    if (i < NN) cnt[i] += btot[blockIdx.x];
}
__global__ __launch_bounds__(256) void fill_kernel(uint* __restrict__ csr, int* __restrict__ cnt,
                                                   const int* __restrict__ ei, const int* __restrict__ ea) {
    int e = blockIdx.x * 256 + threadIdx.x;
    if (e >= EE) return;
    int d = ei[EE + e];
    int pos = atomicAdd(&cnt[d], 1);
    csr[pos] = (uint)ei[e] | ((uint)ea[e] << 16);
}

// ---------------- msg MFMA: block = 32-node tile, wave = 1 edge type, 2 row-tiles ----------------
__global__ __launch_bounds__(256) void msg_mfma4(
    ushort* __restrict__ h4, const ushort* __restrict__ xbf, const ushort* __restrict__ wT) {
    int tid = threadIdx.x;
    int t = tid >> 6, l = tid & 63;
    int node0 = blockIdx.x * 32;
    int lr = l & 15, lk = (l >> 4) * 8;
    bf16x8 af[2][4];
#pragma unroll
    for (int rt = 0; rt < 2; ++rt)
#pragma unroll
        for (int ks = 0; ks < 4; ++ks)
            af[rt][ks] = *(const bf16x8*)&xbf[(size_t)(node0 + rt * 16 + lr) * CC + ks * 32 + lk];
#pragma unroll
    for (int ct = 0; ct < 8; ++ct) {
        bf16x8 bfr[4];
#pragma unroll
        for (int ks = 0; ks < 4; ++ks)
            bfr[ks] = *(const bf16x8*)&wT[(size_t)(t * 128 + ct * 16 + lr) * 128 + ks * 32 + lk];
        fx4 acc0 = {0.f, 0.f, 0.f, 0.f}, acc1 = {0.f, 0.f, 0.f, 0.f};
#pragma unroll
        for (int ks = 0; ks < 4; ++ks) {
            acc0 = __builtin_amdgcn_mfma_f32_16x16x32_bf16(af[0][ks], bfr[ks], acc0, 0, 0, 0);
            acc1 = __builtin_amdgcn_mfma_f32_16x16x32_bf16(af[1][ks], bfr[ks], acc1, 0, 0, 0);
        }
#pragma unroll
        for (int r = 0; r < 4; ++r) {
            int n0 = node0 + (l >> 4) * 4 + r;
            int n1 = n0 + 16;
            if (n0 < NN) h4[((size_t)t * NN + n0) * CC + ct * 16 + lr] = f2b(acc0[r]);
            if (n1 < NN) h4[((size_t)t * NN + n1) * CC + ct * 16 + lr] = f2b(acc1[r]);
        }
    }
}

// ---------------- gather: m[d] = sum h4[type][src] (wave per node) ----------------
__global__ __launch_bounds__(256) void gather_kernel(
    ushort* __restrict__ mbf, const ushort* __restrict__ h4,
    const uint* __restrict__ csr, const int* __restrict__ endp) {
    int w = threadIdx.x >> 6, l = threadIdx.x & 63;
    int node = blockIdx.x * 4 + w;
    int start = (node == 0) ? 0 : endp[node - 1];
    int end = endp[node];
    int c0 = l * 2;
    float s0 = 0.f, s1 = 0.f;
    for (int i = start; i < end; ++i) {
        uint pk = csr[i];
        uint src = pk & 0xFFFFu, t = pk >> 16;
        uint hv = *(const uint*)&h4[(((size_t)t * NN + src) << 7) + c0];
        s0 += b2f((ushort)(hv & 0xFFFFu));
        s1 += b2f((ushort)(hv >> 16));
    }
    *(uint*)&mbf[((size_t)node << 7) + c0] = (uint)f2b(s0) | ((uint)f2b(s1) << 16);
}

// ---------------- GRU MFMA ----------------
__global__ __launch_bounds__(256) void gru_mfma(
    float* __restrict__ x, ushort* __restrict__ xbf, const ushort* __restrict__ mbf,
    const ushort* __restrict__ wgb, const float* __restrict__ cvt) {
    int tid = threadIdx.x;
    int w = tid >> 6, l = tid & 63;
    int node0 = blockIdx.x * 32;
    int lr = l & 15, lk = (l >> 4) * 8;
    bf16x8 mf[2][4], xf[2][4];
#pragma unroll
    for (int rt = 0; rt < 2; ++rt)
#pragma unroll
        for (int ks = 0; ks < 4; ++ks) {
            size_t ro = (size_t)(node0 + rt * 16 + lr) * CC + ks * 32 + lk;
            mf[rt][ks] = *(const bf16x8*)&mbf[ro];
            xf[rt][ks] = *(const bf16x8*)&xbf[ro];
        }
    __syncthreads();
#pragma unroll
    for (int cc = 0; cc < 2; ++cc) {
        int ct = w * 2 + cc;
        int row0 = ct * 16 + lr;
        fx4 ai[3][2], ah[3][2];
#pragma unroll
        for (int s = 0; s < 3; ++s)
#pragma unroll
            for (int rt = 0; rt < 2; ++rt) { ai[s][rt] = (fx4){0,0,0,0}; ah[s][rt] = (fx4){0,0,0,0}; }
#pragma unroll
        for (int ks = 0; ks < 4; ++ks) {
            int ko = ks * 32 + lk;
            bf16x8 bI[3], bH[3];
#pragma unroll
            for (int s = 0; s < 3; ++s) {
                bI[s] = *(const bf16x8*)&wgb[(size_t)(s * 128 + row0) * 128 + ko];
                bH[s] = *(const bf16x8*)&wgb[49152 + (size_t)(s * 128 + row0) * 128 + ko];
            }
#pragma unroll
            for (int s = 0; s < 3; ++s)
#pragma unroll
                for (int rt = 0; rt < 2; ++rt) {
                    ai[s][rt] = __builtin_amdgcn_mfma_f32_16x16x32_bf16(mf[rt][ks], bI[s], ai[s][rt], 0, 0, 0);
                    ah[s][rt] = __builtin_amdgcn_mfma_f32_16x16x32_bf16(xf[rt][ks], bH[s], ah[s][rt], 0, 0, 0);
                }
        }
        float bi0 = cvt[row0],        bh0 = cvt[384 + row0];
        float bi1 = cvt[128 + row0],  bh1 = cvt[512 + row0];
        float bi2 = cvt[256 + row0],  bh2 = cvt[640 + row0];
#pragma unroll
        for (int rt = 0; rt < 2; ++rt)
#pragma unroll
            for (int r = 0; r < 4; ++r) {
                int node = node0 + rt * 16 + (l >> 4) * 4 + r;
                if (node >= NN) continue;
                float rg = sigm(ai[0][rt][r] + bi0 + ah[0][rt][r] + bh0);
                float zg = sigm(ai[1][rt][r] + bi1 + ah[1][rt][r] + bh1);
                float ny = ai[2][rt][r] + bi2 + rg * (ah[2][rt][r] + bh2);
                float ng = 2.f * sigm(2.f * ny) - 1.f;
                size_t xi = (size_t)node * CC + row0;
                float xo = x[xi];
                float xn = (1.f - zg) * ng + zg * xo;
                x[xi] = xn;
                xbf[xi] = f2b(xn);
            }
    }
}

// ---------------- aggregation ----------------
__global__ __launch_bounds__(256) void agg_kernel(
    float* __restrict__ sums, float* __restrict__ cnt, const float* __restrict__ x,
    const int* __restrict__ batch, const int* __restrict__ x_type) {
    int idx = blockIdx.x * 256 + threadIdx.x;
    int n = idx >> 7, c = idx & 127;
    int seg = batch[n] * TT + x_type[n];
    atomicAdd(&sums[seg * CC + c], x[idx]);
    if (c == 0) atomicAdd(&cnt[seg], 1.0f);
}

// ---------------- attnflat: mean + attention + weighted flatten -> bf16 flat[B][2048] ----------------
__global__ __launch_bounds__(256) void attnflat_kernel(
    ushort* __restrict__ flatbf, const float* __restrict__ sums, const float* __restrict__ cnt,
    const float* __restrict__ cvt) {
    __shared__ float agg_s[TT][CC + 1];
    __shared__ float wpart[TT][8];
    __shared__ float attn_s[TT];
    int b = blockIdx.x, tid = threadIdx.x;
#pragma unroll
    for (int q = 0; q < 8; ++q) {
        int idx = tid + q * 256;
        int t = idx >> 7, c = idx & 127;
        float cv = cnt[b * TT + t];
        agg_s[t][c] = cv > 0.f ? sums[(size_t)(b * TT + t) * CC + c] / cv : 0.f;
    }
    __syncthreads();
    if (tid < 128) {
        int t = tid >> 3, p = tid & 7;
        float acc = 0.f;
        for (int i = 0; i < 16; ++i) acc += agg_s[t][p * 16 + i] * cvt[896 + p * 16 + i];
        wpart[t][p] = acc;
    }
    __syncthreads();
    if (tid < 16) {
        float acc = cvt[1034];
        for (int p = 0; p < 8; ++p) acc += wpart[tid][p];
        attn_s[tid] = acc;
    }
    __syncthreads();
    if (tid == 0) {
        float mx = attn_s[0];
        for (int t = 1; t < TT; ++t) mx = fmaxf(mx, attn_s[t]);
        float ssum = 0.f, ex[TT];
        for (int t = 0; t < TT; ++t) { ex[t] = __expf(attn_s[t] - mx); ssum += ex[t]; }
        for (int t = 0; t < TT; ++t) attn_s[t] = ex[t] / ssum;
    }
    __syncthreads();
#pragma unroll
    for (int q = 0; q < 8; ++q) {
        int idx = tid + q * 256;
        int t = idx >> 7, c = idx & 127;
        flatbf[(size_t)b * 2048 + idx] = f2b(agg_s[t][c] * attn_s[t]);
    }
}

// ---------------- enc MFMA: flat[256][2048] @ wencT -> encp[4][256][128] ----------------
__global__ __launch_bounds__(256) void enc_mfma(
    float* __restrict__ encp, const ushort* __restrict__ flatbf, const ushort* __restrict__ wencT) {
    int tid = threadIdx.x;
    int w = tid >> 6, l = tid & 63;
    int bid = blockIdx.x;
    int m0 = (bid >> 2) * 16;          // 16 M-tiles
    int kc = (bid & 3) * 512;          // 4 K-splits
    int lr = l & 15, lk = (l >> 4) * 8;
    fx4 acc0 = {0,0,0,0}, acc1 = {0,0,0,0};
    int ct0 = w * 2, ct1 = w * 2 + 1;
#pragma unroll
    for (int ks = 0; ks < 16; ++ks) {
        int ko = kc + ks * 32 + lk;
        bf16x8 af = *(const bf16x8*)&flatbf[(size_t)(m0 + lr) * 2048 + ko];
        bf16x8 b0 = *(const bf16x8*)&wencT[(size_t)(ct0 * 16 + lr) * 2048 + ko];
        bf16x8 b1 = *(const bf16x8*)&wencT[(size_t)(ct1 * 16 + lr) * 2048 + ko];
        acc0 = __builtin_amdgcn_mfma_f32_16x16x32_bf16(af, b0, acc0, 0, 0, 0);
        acc1 = __builtin_amdgcn_mfma_f32_16x16x32_bf16(af, b1, acc1, 0, 0, 0);
    }
#pragma unroll
    for (int r = 0; r < 4; ++r) {
        int row = m0 + (l >> 4) * 4 + r;
        encp[(size_t)(bid & 3) * BB * ENC + (size_t)row * ENC + ct0 * 16 + lr] = acc0[r];
        encp[(size_t)(bid & 3) * BB * ENC + (size_t)row * ENC + ct1 * 16 + lr] = acc1[r];
    }
}

// ---------------- dec: reduce partials + bias, then 10-class head ----------------
__global__ __launch_bounds__(256) void dec_kernel(
    void* __restrict__ out, const float* __restrict__ encp, const float* __restrict__ cvt,
    const int* __restrict__ flag) {
    const int isf = *flag;
    __shared__ float encs[ENC];
    int b = blockIdx.x, tid = threadIdx.x;
    if (tid < 128) {
        float e = cvt[768 + tid];
#pragma unroll
        for (int p = 0; p < 4; ++p) e += encp[(size_t)p * BB * ENC + (size_t)b * ENC + tid];
        encs[tid] = e;
    }
    __syncthreads();
    if (tid < NCLS) {
        float acc = cvt[1024 + tid];
        for (int j = 0; j < ENC; ++j) acc += encs[j] * cvt[1040 + j * NCLS + tid];
        int oi = b * NCLS + tid;
        if (isf) ((float*)out)[oi] = acc;
        else ((ushort*)out)[oi] = f2b(acc);
    }
}

extern "C" void kernel_launch(void* const* d_in, const int* in_sizes, int n_in,
                              void* d_out, int out_size, void* d_ws, size_t ws_size,
                              hipStream_t stream) {
    const int* x_type      = (const int*)d_in[0];
    const int* x_attrs     = (const int*)d_in[1];
    const int* x_mask      = (const int*)d_in[2];
    const int* edge_index  = (const int*)d_in[3];
    const int* edge_attr   = (const int*)d_in[4];
    const int* batch       = (const int*)d_in[6];
    const void* type_emb   = d_in[7];
    const void* attr_emb   = d_in[8];
    const void* W_msg      = d_in[9];
    const void* W_ih       = d_in[10];
    const void* W_hh       = d_in[11];
    const void* b_ih       = d_in[12];
    const void* b_hh       = d_in[13];
    const void* w_attn     = d_in[14];
    const void* b_attn     = d_in[15];
    const void* W_enc      = d_in[16];
    const void* b_enc      = d_in[17];
    const void* W_dec      = d_in[18];
    const void* b_dec      = d_in[19];

    char* p = (char*)d_ws;
    float*  x     = (float*)p;           p += (size_t)NN * CC * 4;       // 25.6 MB
    ushort* xbf   = (ushort*)p;          p += (size_t)NN * CC * 2;       // 12.8 MB
    ushort* mbf   = (ushort*)p;          p += (size_t)NN * CC * 2;       // 12.8 MB
    ushort* h4    = (ushort*)p;          p += (size_t)4 * NN * CC * 2;   // 51.2 MB
    ushort* wT    = (ushort*)p;          p += (size_t)16 * 128 * 128 * 2;
    ushort* wgb   = (ushort*)p;          p += (size_t)2 * 384 * 128 * 2;
    ushort* wencT = (ushort*)p;          p += (size_t)ENC * 2048 * 2;    // 512 KB
    ushort* flatbf= (ushort*)p;          p += (size_t)BB * 2048 * 2;     // 1 MB
    float*  encp  = (float*)p;           p += (size_t)4 * BB * ENC * 4;  // 512 KB
    float*  cvt   = (float*)p;           p += 2320 * 4;
    float*  sums  = (float*)p;           p += (size_t)BB * TT * CC * 4;
    float*  cnta  = (float*)p;           p += (size_t)BB * TT * 4;
    uint*   csr   = (uint*)p;            p += (size_t)EE * 4;
    int*    cptr  = (int*)p;             p += (size_t)NN * 4;
    int*    btot  = (int*)p;             p += 256 * 4;
    int*    flag  = (int*)p;

    sniff_kernel<<<1, 1, 0, stream>>>(flag, W_enc);
    wmsgT_kernel<<<1024, 256, 0, stream>>>(wT, W_msg, flag);
    wgru_kernel<<<384, 256, 0, stream>>>(wgb, W_ih, W_hh, flag);
    wencT_kernel<<<1024, 256, 0, stream>>>(wencT, W_enc, flag);
    bconv_kernel<<<10, 256, 0, stream>>>(cvt, b_ih, b_hh, b_enc, w_attn, b_dec, b_attn, W_dec, flag);
    embed_kernel<<<(NN * 64) / 256, 256, 0, stream>>>(x, xbf, x_type, x_attrs, x_mask,
                                                      type_emb, attr_emb, flag);

    // ---- CSR build ----
    const int NB = (NN + 255) / 256;
    hipMemsetAsync(cptr, 0, (size_t)NN * sizeof(int), stream);
    deg_kernel<<<(EE + 255) / 256, 256, 0, stream>>>(cptr, edge_index);
    scan1_kernel<<<NB, 256, 0, stream>>>(cptr, btot);
    scan2_kernel<<<1, 256, 0, stream>>>(btot, NB);
    scan3_kernel<<<NB, 256, 0, stream>>>(cptr, btot);
    fill_kernel<<<(EE + 255) / 256, 256, 0, stream>>>(csr, cptr, edge_index, edge_attr);

    const int tile_grid = (NN + 31) / 32;   // 1563
    for (int l = 0; l < LL; ++l) {
        msg_mfma4<<<tile_grid, 256, 0, stream>>>(h4, xbf, wT + (size_t)l * 4 * 128 * 128);
        gather_kernel<<<NN / 4, 256, 0, stream>>>(mbf, h4, csr, cptr);
        gru_mfma<<<tile_grid, 256, 0, stream>>>(x, xbf, mbf, wgb, cvt);
    }

    hipMemsetAsync(sums, 0, (size_t)(BB * TT * CC + BB * TT) * sizeof(float), stream);
    agg_kernel<<<(NN * CC) / 256, 256, 0, stream>>>(sums, cnta, x, batch, x_type);
    attnflat_kernel<<<BB, 256, 0, stream>>>(flatbf, sums, cnta, cvt);
    enc_mfma<<<64, 256, 0, stream>>>(encp, flatbf, wencT);
    dec_kernel<<<BB, 256, 0, stream>>>(d_out, encp, cvt, flag);
}

// Round 10
// 797.674 us; speedup vs baseline: 5.2495x; 1.0662x over previous
//
#include <hip/hip_runtime.h>
#include <hip/hip_bf16.h>

#define NN 50000
#define EE 600000
#define AA 8
#define CC 128
#define TT 16
#define TE 4
#define LL 4
#define BB 256
#define ENC 128
#define NCLS 10

typedef __attribute__((ext_vector_type(8))) short bf16x8;
typedef __attribute__((ext_vector_type(4))) float fx4;
typedef __attribute__((ext_vector_type(4))) uint ux4;

__device__ __forceinline__ float b2f(ushort u) {
    union { float f; uint32_t i; } v; v.i = ((uint32_t)u) << 16; return v.f;
}
__device__ __forceinline__ ushort f2b(float f) {
    union { float f; uint32_t i; } v; v.f = f;
    uint32_t x = v.i;
    x += 0x7FFFu + ((x >> 16) & 1u);
    return (ushort)(x >> 16);
}
__device__ __forceinline__ float ldw(const void* p, long i, int isf) {
    return isf ? ((const float*)p)[i] : b2f(((const ushort*)p)[i]);
}
__device__ __forceinline__ float sigm(float t) { return 1.f / (1.f + __expf(-t)); }

// ---------------- dtype sniff ----------------
__global__ void sniff_kernel(int* flag, const void* W_enc_raw) {
    const ushort* u = (const ushort*)W_enc_raw;
    int good = 0;
    for (int i = 0; i < 256; ++i) {
        ushort v = u[i];
        int ex = (v >> 7) & 0xFF;
        if (v == 0 || (ex >= 100 && ex <= 126)) ++good;
    }
    *flag = (good >= 230) ? 0 : 1;   // 0 = bf16, 1 = f32
}

// ---------------- transpose all W_msg into wT[l*4+t][d][c] (bf16) ----------------
__global__ __launch_bounds__(256) void wmsgT_kernel(ushort* __restrict__ wT,
                                                    const void* __restrict__ W,
                                                    const int* __restrict__ flag) {
    const int isf = *flag;
    int idx = blockIdx.x * 256 + threadIdx.x;
    int lt = idx >> 14, rem = idx & 16383, d = rem >> 7, c = rem & 127;
    long src = ((long)lt << 14) + c * 128 + d;
    wT[idx] = isf ? f2b(((const float*)W)[src]) : ((const ushort*)W)[src];
}

// ---------------- Wih||Whh -> bf16 ----------------
__global__ __launch_bounds__(256) void wgru_kernel(ushort* __restrict__ wgb,
                                                   const void* __restrict__ Wih,
                                                   const void* __restrict__ Whh,
                                                   const int* __restrict__ flag) {
    const int isf = *flag;
    int idx = blockIdx.x * 256 + threadIdx.x;
    if (idx >= 98304) return;
    int ih = (idx < 49152);
    int off = ih ? idx : idx - 49152;
    wgb[idx] = f2b(ldw(ih ? Wih : Whh, off, isf));
}

// ---------------- W_enc -> bf16 transposed [ENC][2048] ----------------
__global__ __launch_bounds__(256) void wencT_kernel(ushort* __restrict__ wencT,
                                                    const void* __restrict__ W_enc,
                                                    const int* __restrict__ flag) {
    const int isf = *flag;
    int idx = blockIdx.x * 256 + threadIdx.x;
    int j = idx >> 11, k = idx & 2047;
    wencT[idx] = f2b(ldw(W_enc, (long)k * ENC + j, isf));
}

// ---------------- small params -> f32 scratch ----------------
// 0 bih(384) | 384 bhh(384) | 768 b_enc(128) | 896 w_attn(128)
// 1024 b_dec(10) | 1034 b_attn(1) | 1040 W_dec(1280) | total 2320
__global__ __launch_bounds__(256) void bconv_kernel(float* __restrict__ cvt,
                                                    const void* __restrict__ bih, const void* __restrict__ bhh,
                                                    const void* __restrict__ b_enc, const void* __restrict__ w_attn,
                                                    const void* __restrict__ b_dec, const void* __restrict__ b_attn,
                                                    const void* __restrict__ W_dec,
                                                    const int* __restrict__ flag) {
    const int isf = *flag;
    int i = blockIdx.x * 256 + threadIdx.x;
    if (i < 384) cvt[i] = ldw(bih, i, isf);
    else if (i < 768) cvt[i] = ldw(bhh, i - 384, isf);
    else if (i < 896) cvt[i] = ldw(b_enc, i - 768, isf);
    else if (i < 1024) cvt[i] = ldw(w_attn, i - 896, isf);
    else if (i < 1034) cvt[i] = ldw(b_dec, i - 1024, isf);
    else if (i == 1034) cvt[i] = ldw(b_attn, 0, isf);
    else if (i >= 1040 && i < 2320) cvt[i] = ldw(W_dec, i - 1040, isf);
}

// ---------------- embed: bf16 state only ----------------
__global__ __launch_bounds__(256) void embed_kernel(
    ushort* __restrict__ xbf,
    const int* __restrict__ x_type, const int* __restrict__ x_attrs,
    const int* __restrict__ x_mask, const void* __restrict__ type_emb,
    const void* __restrict__ attr_emb, const int* __restrict__ flag) {
    const int isf = *flag;
    int idx = blockIdx.x * 256 + threadIdx.x;
    int n = idx >> 6, c = idx & 63;
    if (n >= NN) return;
    int ty = x_type[n];
    xbf[n * CC + c] = f2b(ldw(type_emb, ty * 64 + c, isf));
    int cnt = x_mask[n];
    float s = 0.f;
    for (int a = 0; a < cnt; ++a) s += ldw(attr_emb, x_attrs[n * AA + a] * 64 + c, isf);
    xbf[n * CC + 64 + c] = f2b(s / (float)cnt);
}

// ---------------- CSR build ----------------
__global__ __launch_bounds__(256) void deg_kernel(int* __restrict__ cnt, const int* __restrict__ ei) {
    int e = blockIdx.x * 256 + threadIdx.x;
    if (e < EE) atomicAdd(&cnt[ei[EE + e]], 1);
}
__global__ __launch_bounds__(256) void scan1_kernel(int* __restrict__ cnt, int* __restrict__ btot) {
    __shared__ int s[256];
    int tid = threadIdx.x, i = blockIdx.x * 256 + tid;
    int v = (i < NN) ? cnt[i] : 0;
    s[tid] = v; __syncthreads();
    for (int off = 1; off < 256; off <<= 1) {
        int t = (tid >= off) ? s[tid - off] : 0; __syncthreads();
        s[tid] += t; __syncthreads();
    }
    if (i < NN) cnt[i] = s[tid] - v;
    if (tid == 255) btot[blockIdx.x] = s[255];
}
__global__ __launch_bounds__(256) void scan2_kernel(int* __restrict__ btot, int nb) {
    __shared__ int s[256];
    int tid = threadIdx.x;
    int v = (tid < nb) ? btot[tid] : 0;
    s[tid] = v; __syncthreads();
    for (int off = 1; off < 256; off <<= 1) {
        int t = (tid >= off) ? s[tid - off] : 0; __syncthreads();
        s[tid] += t; __syncthreads();
    }
    if (tid < nb) btot[tid] = s[tid] - v;
}
__global__ __launch_bounds__(256) void scan3_kernel(int* __restrict__ cnt, const int* __restrict__ btot) {
    int i = blockIdx.x * 256 + threadIdx.x;
    if (i < NN) cnt[i] += btot[blockIdx.x];
}
__global__ __launch_bounds__(256) void fill_kernel(uint* __restrict__ csr, int* __restrict__ cnt,
                                                   const int* __restrict__ ei, const int* __restrict__ ea) {
    int e = blockIdx.x * 256 + threadIdx.x;
    if (e >= EE) return;
    int d = ei[EE + e];
    int pos = atomicAdd(&cnt[d], 1);
    csr[pos] = (uint)ei[e] | ((uint)ea[e] << 16);
}

// ---------------- msg MFMA: 32-node tile, wave=type; LDS-repacked dwordx4 stores ----------------
__global__ __launch_bounds__(256) void msg_mfma4(
    ushort* __restrict__ h4, const ushort* __restrict__ xbf, const ushort* __restrict__ wT) {
    __shared__ ushort h_s[4][32][128];   // 32 KB
    int tid = threadIdx.x;
    int t = tid >> 6, l = tid & 63;
    int node0 = blockIdx.x * 32;
    int lr = l & 15, lk = (l >> 4) * 8;
    bf16x8 af[2][4];
#pragma unroll
    for (int rt = 0; rt < 2; ++rt)
#pragma unroll
        for (int ks = 0; ks < 4; ++ks)
            af[rt][ks] = *(const bf16x8*)&xbf[(size_t)(node0 + rt * 16 + lr) * CC + ks * 32 + lk];
#pragma unroll
    for (int ct = 0; ct < 8; ++ct) {
        bf16x8 bfr[4];
#pragma unroll
        for (int ks = 0; ks < 4; ++ks)
            bfr[ks] = *(const bf16x8*)&wT[(size_t)(t * 128 + ct * 16 + lr) * 128 + ks * 32 + lk];
        fx4 acc0 = {0.f, 0.f, 0.f, 0.f}, acc1 = {0.f, 0.f, 0.f, 0.f};
#pragma unroll
        for (int ks = 0; ks < 4; ++ks) {
            acc0 = __builtin_amdgcn_mfma_f32_16x16x32_bf16(af[0][ks], bfr[ks], acc0, 0, 0, 0);
            acc1 = __builtin_amdgcn_mfma_f32_16x16x32_bf16(af[1][ks], bfr[ks], acc1, 0, 0, 0);
        }
#pragma unroll
        for (int r = 0; r < 4; ++r) {
            int nl = (l >> 4) * 4 + r;
            h_s[t][nl][ct * 16 + lr]      = f2b(acc0[r]);
            h_s[t][nl + 16][ct * 16 + lr] = f2b(acc1[r]);
        }
    }
    __syncthreads();
    // cooperative store: 2048 uint4 total, 8 per thread
    const uint* ls = (const uint*)&h_s[0][0][0];
#pragma unroll
    for (int q = 0; q < 8; ++q) {
        int i4 = q * 256 + tid;
        int t2 = i4 >> 9, rem = i4 & 511;
        int node = rem >> 4, chunk = rem & 15;
        if (node0 + node < NN) {
            ux4 v = *(const ux4*)&ls[i4 * 4];
            *(ux4*)&h4[((size_t)t2 * NN + node0 + node) * CC + chunk * 8] = v;
        }
    }
}

// ---------------- gather: m[d] = sum h4[type][src] (wave per node) ----------------
__global__ __launch_bounds__(256) void gather_kernel(
    ushort* __restrict__ mbf, const ushort* __restrict__ h4,
    const uint* __restrict__ csr, const int* __restrict__ endp) {
    int w = threadIdx.x >> 6, l = threadIdx.x & 63;
    int node = blockIdx.x * 4 + w;
    int start = (node == 0) ? 0 : endp[node - 1];
    int end = endp[node];
    int c0 = l * 2;
    float s0 = 0.f, s1 = 0.f;
    for (int i = start; i < end; ++i) {
        uint pk = csr[i];
        uint src = pk & 0xFFFFu, t = pk >> 16;
        uint hv = *(const uint*)&h4[(((size_t)t * NN + src) << 7) + c0];
        s0 += b2f((ushort)(hv & 0xFFFFu));
        s1 += b2f((ushort)(hv >> 16));
    }
    *(uint*)&mbf[((size_t)node << 7) + c0] = (uint)f2b(s0) | ((uint)f2b(s1) << 16);
}

// ---------------- GRU MFMA (bf16 state; optional fused aggregation) ----------------
template <int AGG>
__global__ __launch_bounds__(256) void gru_mfma(
    ushort* __restrict__ xbf, const ushort* __restrict__ mbf,
    const ushort* __restrict__ wgb, const float* __restrict__ cvt,
    float* __restrict__ sums, float* __restrict__ cnta,
    const int* __restrict__ batch, const int* __restrict__ x_type) {
    int tid = threadIdx.x;
    int w = tid >> 6, l = tid & 63;
    int node0 = blockIdx.x * 32;
    int lr = l & 15, lk = (l >> 4) * 8;
    bf16x8 mf[2][4], xf[2][4];
#pragma unroll
    for (int rt = 0; rt < 2; ++rt)
#pragma unroll
        for (int ks = 0; ks < 4; ++ks) {
            size_t ro = (size_t)(node0 + rt * 16 + lr) * CC + ks * 32 + lk;
            mf[rt][ks] = *(const bf16x8*)&mbf[ro];
            xf[rt][ks] = *(const bf16x8*)&xbf[ro];
        }
    __syncthreads();   // all waves' A-frags in regs before any epilogue write to xbf
#pragma unroll
    for (int cc = 0; cc < 2; ++cc) {
        int ct = w * 2 + cc;
        int row0 = ct * 16 + lr;
        fx4 ai[3][2], ah[3][2];
#pragma unroll
        for (int s = 0; s < 3; ++s)
#pragma unroll
            for (int rt = 0; rt < 2; ++rt) { ai[s][rt] = (fx4){0,0,0,0}; ah[s][rt] = (fx4){0,0,0,0}; }
#pragma unroll
        for (int ks = 0; ks < 4; ++ks) {
            int ko = ks * 32 + lk;
            bf16x8 bI[3], bH[3];
#pragma unroll
            for (int s = 0; s < 3; ++s) {
                bI[s] = *(const bf16x8*)&wgb[(size_t)(s * 128 + row0) * 128 + ko];
                bH[s] = *(const bf16x8*)&wgb[49152 + (size_t)(s * 128 + row0) * 128 + ko];
            }
#pragma unroll
            for (int s = 0; s < 3; ++s)
#pragma unroll
                for (int rt = 0; rt < 2; ++rt) {
                    ai[s][rt] = __builtin_amdgcn_mfma_f32_16x16x32_bf16(mf[rt][ks], bI[s], ai[s][rt], 0, 0, 0);
                    ah[s][rt] = __builtin_amdgcn_mfma_f32_16x16x32_bf16(xf[rt][ks], bH[s], ah[s][rt], 0, 0, 0);
                }
        }
        float bi0 = cvt[row0],        bh0 = cvt[384 + row0];
        float bi1 = cvt[128 + row0],  bh1 = cvt[512 + row0];
        float bi2 = cvt[256 + row0],  bh2 = cvt[640 + row0];
#pragma unroll
        for (int rt = 0; rt < 2; ++rt)
#pragma unroll
            for (int r = 0; r < 4; ++r) {
                int node = node0 + rt * 16 + (l >> 4) * 4 + r;
                if (node >= NN) continue;
                float rg = sigm(ai[0][rt][r] + bi0 + ah[0][rt][r] + bh0);
                float zg = sigm(ai[1][rt][r] + bi1 + ah[1][rt][r] + bh1);
                float ny = ai[2][rt][r] + bi2 + rg * (ah[2][rt][r] + bh2);
                float ng = 2.f * sigm(2.f * ny) - 1.f;
                size_t xi = (size_t)node * CC + row0;
                float xo = b2f(xbf[xi]);
                float xn = (1.f - zg) * ng + zg * xo;
                xbf[xi] = f2b(xn);
                if (AGG) {
                    int seg = batch[node] * TT + x_type[node];
                    atomicAdd(&sums[(size_t)seg * CC + row0], xn);
                    if (row0 == 0) atomicAdd(&cnta[seg], 1.0f);
                }
            }
    }
}

// ---------------- attnflat: mean + attention + weighted flatten -> bf16 flat[B][2048] ----------------
__global__ __launch_bounds__(256) void attnflat_kernel(
    ushort* __restrict__ flatbf, const float* __restrict__ sums, const float* __restrict__ cnt,
    const float* __restrict__ cvt) {
    __shared__ float agg_s[TT][CC + 1];
    __shared__ float wpart[TT][8];
    __shared__ float attn_s[TT];
    int b = blockIdx.x, tid = threadIdx.x;
#pragma unroll
    for (int q = 0; q < 8; ++q) {
        int idx = tid + q * 256;
        int t = idx >> 7, c = idx & 127;
        float cv = cnt[b * TT + t];
        agg_s[t][c] = cv > 0.f ? sums[(size_t)(b * TT + t) * CC + c] / cv : 0.f;
    }
    __syncthreads();
    if (tid < 128) {
        int t = tid >> 3, p = tid & 7;
        float acc = 0.f;
        for (int i = 0; i < 16; ++i) acc += agg_s[t][p * 16 + i] * cvt[896 + p * 16 + i];
        wpart[t][p] = acc;
    }
    __syncthreads();
    if (tid < 16) {
        float acc = cvt[1034];
        for (int p = 0; p < 8; ++p) acc += wpart[tid][p];
        attn_s[tid] = acc;
    }
    __syncthreads();
    if (tid == 0) {
        float mx = attn_s[0];
        for (int t = 1; t < TT; ++t) mx = fmaxf(mx, attn_s[t]);
        float ssum = 0.f, ex[TT];
        for (int t = 0; t < TT; ++t) { ex[t] = __expf(attn_s[t] - mx); ssum += ex[t]; }
        for (int t = 0; t < TT; ++t) attn_s[t] = ex[t] / ssum;
    }
    __syncthreads();
#pragma unroll
    for (int q = 0; q < 8; ++q) {
        int idx = tid + q * 256;
        int t = idx >> 7, c = idx & 127;
        flatbf[(size_t)b * 2048 + idx] = f2b(agg_s[t][c] * attn_s[t]);
    }
}

// ---------------- enc MFMA ----------------
__global__ __launch_bounds__(256) void enc_mfma(
    float* __restrict__ encp, const ushort* __restrict__ flatbf, const ushort* __restrict__ wencT) {
    int tid = threadIdx.x;
    int w = tid >> 6, l = tid & 63;
    int bid = blockIdx.x;
    int m0 = (bid >> 2) * 16;
    int kc = (bid & 3) * 512;
    int lr = l & 15, lk = (l >> 4) * 8;
    fx4 acc0 = {0,0,0,0}, acc1 = {0,0,0,0};
    int ct0 = w * 2, ct1 = w * 2 + 1;
#pragma unroll
    for (int ks = 0; ks < 16; ++ks) {
        int ko = kc + ks * 32 + lk;
        bf16x8 af = *(const bf16x8*)&flatbf[(size_t)(m0 + lr) * 2048 + ko];
        bf16x8 b0 = *(const bf16x8*)&wencT[(size_t)(ct0 * 16 + lr) * 2048 + ko];
        bf16x8 b1 = *(const bf16x8*)&wencT[(size_t)(ct1 * 16 + lr) * 2048 + ko];
        acc0 = __builtin_amdgcn_mfma_f32_16x16x32_bf16(af, b0, acc0, 0, 0, 0);
        acc1 = __builtin_amdgcn_mfma_f32_16x16x32_bf16(af, b1, acc1, 0, 0, 0);
    }
#pragma unroll
    for (int r = 0; r < 4; ++r) {
        int row = m0 + (l >> 4) * 4 + r;
        encp[(size_t)(bid & 3) * BB * ENC + (size_t)row * ENC + ct0 * 16 + lr] = acc0[r];
        encp[(size_t)(bid & 3) * BB * ENC + (size_t)row * ENC + ct1 * 16 + lr] = acc1[r];
    }
}

// ---------------- dec ----------------
__global__ __launch_bounds__(256) void dec_kernel(
    void* __restrict__ out, const float* __restrict__ encp, const float* __restrict__ cvt,
    const int* __restrict__ flag) {
    const int isf = *flag;
    __shared__ float encs[ENC];
    int b = blockIdx.x, tid = threadIdx.x;
    if (tid < 128) {
        float e = cvt[768 + tid];
#pragma unroll
        for (int p = 0; p < 4; ++p) e += encp[(size_t)p * BB * ENC + (size_t)b * ENC + tid];
        encs[tid] = e;
    }
    __syncthreads();
    if (tid < NCLS) {
        float acc = cvt[1024 + tid];
        for (int j = 0; j < ENC; ++j) acc += encs[j] * cvt[1040 + j * NCLS + tid];
        int oi = b * NCLS + tid;
        if (isf) ((float*)out)[oi] = acc;
        else ((ushort*)out)[oi] = f2b(acc);
    }
}

extern "C" void kernel_launch(void* const* d_in, const int* in_sizes, int n_in,
                              void* d_out, int out_size, void* d_ws, size_t ws_size,
                              hipStream_t stream) {
    const int* x_type      = (const int*)d_in[0];
    const int* x_attrs     = (const int*)d_in[1];
    const int* x_mask      = (const int*)d_in[2];
    const int* edge_index  = (const int*)d_in[3];
    const int* edge_attr   = (const int*)d_in[4];
    const int* batch       = (const int*)d_in[6];
    const void* type_emb   = d_in[7];
    const void* attr_emb   = d_in[8];
    const void* W_msg      = d_in[9];
    const void* W_ih       = d_in[10];
    const void* W_hh       = d_in[11];
    const void* b_ih       = d_in[12];
    const void* b_hh       = d_in[13];
    const void* w_attn     = d_in[14];
    const void* b_attn     = d_in[15];
    const void* W_enc      = d_in[16];
    const void* b_enc      = d_in[17];
    const void* W_dec      = d_in[18];
    const void* b_dec      = d_in[19];

    char* p = (char*)d_ws;
    ushort* xbf   = (ushort*)p;          p += (size_t)NN * CC * 2;       // 12.8 MB
    ushort* mbf   = (ushort*)p;          p += (size_t)NN * CC * 2;       // 12.8 MB
    ushort* h4    = (ushort*)p;          p += (size_t)4 * NN * CC * 2;   // 51.2 MB
    ushort* wT    = (ushort*)p;          p += (size_t)16 * 128 * 128 * 2;
    ushort* wgb   = (ushort*)p;          p += (size_t)2 * 384 * 128 * 2;
    ushort* wencT = (ushort*)p;          p += (size_t)ENC * 2048 * 2;
    ushort* flatbf= (ushort*)p;          p += (size_t)BB * 2048 * 2;
    float*  encp  = (float*)p;           p += (size_t)4 * BB * ENC * 4;
    float*  cvt   = (float*)p;           p += 2320 * 4;
    float*  sums  = (float*)p;           p += (size_t)BB * TT * CC * 4;
    float*  cnta  = (float*)p;           p += (size_t)BB * TT * 4;
    uint*   csr   = (uint*)p;            p += (size_t)EE * 4;
    int*    cptr  = (int*)p;             p += (size_t)NN * 4;
    int*    btot  = (int*)p;             p += 256 * 4;
    int*    flag  = (int*)p;

    sniff_kernel<<<1, 1, 0, stream>>>(flag, W_enc);
    wmsgT_kernel<<<1024, 256, 0, stream>>>(wT, W_msg, flag);
    wgru_kernel<<<384, 256, 0, stream>>>(wgb, W_ih, W_hh, flag);
    wencT_kernel<<<1024, 256, 0, stream>>>(wencT, W_enc, flag);
    bconv_kernel<<<10, 256, 0, stream>>>(cvt, b_ih, b_hh, b_enc, w_attn, b_dec, b_attn, W_dec, flag);
    embed_kernel<<<(NN * 64) / 256, 256, 0, stream>>>(xbf, x_type, x_attrs, x_mask,
                                                      type_emb, attr_emb, flag);

    // ---- CSR build ----
    const int NB = (NN + 255) / 256;
    hipMemsetAsync(cptr, 0, (size_t)NN * sizeof(int), stream);
    deg_kernel<<<(EE + 255) / 256, 256, 0, stream>>>(cptr, edge_index);
    scan1_kernel<<<NB, 256, 0, stream>>>(cptr, btot);
    scan2_kernel<<<1, 256, 0, stream>>>(btot, NB);
    scan3_kernel<<<NB, 256, 0, stream>>>(cptr, btot);
    fill_kernel<<<(EE + 255) / 256, 256, 0, stream>>>(csr, cptr, edge_index, edge_attr);

    // sums/cnta zeroed once; filled by fused AGG in the last gru
    hipMemsetAsync(sums, 0, (size_t)(BB * TT * CC + BB * TT) * sizeof(float), stream);

    const int tile_grid = (NN + 31) / 32;   // 1563
    for (int l = 0; l < LL; ++l) {
        msg_mfma4<<<tile_grid, 256, 0, stream>>>(h4, xbf, wT + (size_t)l * 4 * 128 * 128);
        gather_kernel<<<NN / 4, 256, 0, stream>>>(mbf, h4, csr, cptr);
        if (l < LL - 1)
            gru_mfma<0><<<tile_grid, 256, 0, stream>>>(xbf, mbf, wgb, cvt, sums, cnta, batch, x_type);
        else
            gru_mfma<1><<<tile_grid, 256, 0, stream>>>(xbf, mbf, wgb, cvt, sums, cnta, batch, x_type);
    }

    attnflat_kernel<<<BB, 256, 0, stream>>>(flatbf, sums, cnta, cvt);
    enc_mfma<<<64, 256, 0, stream>>>(encp, flatbf, wencT);
    dec_kernel<<<BB, 256, 0, stream>>>(d_out, encp, cvt, flag);
}